// Round 2
// baseline (2900.621 us; speedup 1.0000x reference)
//
#include <hip/hip_runtime.h>
#include <hip/hip_bf16.h>

#define E_EDGES 500000
#define NENT    100000
#define NREL    237
#define DIM     100
#define TDIM    300
#define TWO_E   1000000
#define BN_EPS  1e-5f
#define RELSTRIDE 23744
#define REL_COPIES 8

typedef unsigned short u16;
typedef unsigned int   u32;

// ---------- ws layout (offsets in floats) ----------
static const size_t OFF_HS     = 0;          // N*DIM accum (zeroed)
static const size_t OFF_EBS    = 10000000;   // N        (zeroed)
static const size_t OFF_DEG    = 10100000;   // N        (zeroed)
static const size_t OFF_RELCNT = 10200000;   // 256      (zeroed)
static const size_t OFF_RELACC = 10200256;   // 8*23744  (zeroed)
static const size_t OFF_S1     = 10390208;   // 128      (zeroed)
static const size_t OFF_S2     = 10390336;   // 128      (zeroed)
static const size_t OFF_S2R    = 10390464;   // 128      (zeroed)
static const size_t OFF_SC     = 10390592;   // 128      (zeroed)
static const size_t OFF_SC2    = 10390720;   // 128      (zeroed)
static const size_t ZERO_END   = 10390848;   // memset covers [0, ZERO_END)
static const size_t OFF_SCALE0 = 10390848;   // 320
static const size_t OFF_SHIFT0 = 10391168;   // 320
static const size_t OFF_BP     = 10391488;   // 128
static const size_t OFF_SCALE1 = 10391616;   // 128
static const size_t OFF_SHIFT1 = 10391744;   // 128
static const size_t OFF_WPT    = 10391872;   // 100*200  folded W for ent, [d][kk]
static const size_t OFF_WRELT  = 10411872;   // 100*100  folded W for rel, [d][k]
static const size_t OFF_V      = 10421872;   // 23744 (237*100 f32)
static const size_t OFF_U      = 10445616;   // bf16 area: UE = N*200 ushorts (U0|U1 interleaved per row)
static const size_t TOTAL_F    = 20445616;   // ~81.8 MB

__device__ __forceinline__ float bf2f(u16 u){ return __uint_as_float(((u32)u)<<16); }
__device__ __forceinline__ u16 f2bf(float f){
  u32 x = __float_as_uint(f);
  x += 0x7FFFu + ((x>>16)&1u);
  return (u16)(x>>16);
}
__device__ __forceinline__ void ld4a(const u16* p, float* o){
  ushort4 u = *(const ushort4*)p;
  o[0]=bf2f(u.x); o[1]=bf2f(u.y); o[2]=bf2f(u.z); o[3]=bf2f(u.w);
}
__device__ __forceinline__ void ld4f(const float* p, float* o){
  float4 v = *(const float4*)p;
  o[0]=v.x; o[1]=v.y; o[2]=v.z; o[3]=v.w;
}

// ---- histograms: deg(n) = #t0 + #t1 ; relcnt(r) = #t2 ----
__global__ void k_hist(const int* __restrict__ trip, float* __restrict__ deg, float* __restrict__ relcnt){
  int e = blockIdx.x*256 + threadIdx.x;
  if (e >= E_EDGES) return;
  int3 t = ((const int3*)trip)[e];
  atomicAdd(&deg[t.x], 1.0f);
  atomicAdd(&deg[t.y], 1.0f);
  atomicAdd(&relcnt[t.z], 1.0f);
}

// ---- bn0 stats for entity columns via degree-weighted sums ----
__global__ void k_entstats(const float* __restrict__ ent, const float* __restrict__ deg,
                           float* __restrict__ S1, float* __restrict__ S2){
  int d = threadIdx.x;            // blockDim 128, d<100 active
  if (d >= DIM) return;
  int n0 = blockIdx.x*256;
  int nend = n0+256; if (nend > NENT) nend = NENT;
  float s1=0.f, s2=0.f;
  for (int n=n0;n<nend;n++){
    float w = deg[n];
    float x = ent[(size_t)n*DIM + d];
    s1 += w*x;
    s2 += w*x*x;
  }
  atomicAdd(&S1[d], s1);
  atomicAdd(&S2[d], s2);
}

__global__ void k_relstats(const float* __restrict__ rel, const float* __restrict__ relcnt, float* __restrict__ S2r){
  int d = threadIdx.x;            // blockDim 128
  if (d >= DIM) return;
  float s=0.f;
  for (int r=0;r<NREL;r++){
    float x = rel[r*DIM+d];
    s += relcnt[r]*x*x;
  }
  S2r[d] = s;
}

// ---- bn0 scale/shift per column (300) ----
__global__ void k_scale0(const float* __restrict__ g0, const float* __restrict__ b0,
                         const float* __restrict__ S1, const float* __restrict__ S2, const float* __restrict__ S2r,
                         float* __restrict__ scale0, float* __restrict__ shift0){
  int j = threadIdx.x;            // blockDim 320
  if (j >= TDIM) return;
  float mean, var;
  if (j < 200){
    int d = (j<100)? j : j-100;
    mean = S1[d] * (1.0f/TWO_E);
    var  = S2[d] * (1.0f/TWO_E) - mean*mean;
  } else {
    mean = 0.0f;                  // {rel, -rel} -> exact zero mean
    var  = S2r[j-200] * (1.0f/E_EDGES);
  }
  float sc = g0[j] * rsqrtf(var + BN_EPS);
  scale0[j] = sc;
  shift0[j] = b0[j] - mean*sc;
}

// ---- fold scale0 into W: Wpt[d][kk] (kk<100 -> W0 col, else W1 col); Wrelt[d][k] ----
__global__ void k_foldW(const float* __restrict__ aW, const float* __restrict__ scale0,
                        float* __restrict__ Wpt, float* __restrict__ Wrelt){
  int idx = blockIdx.x*256 + threadIdx.x;
  if (idx < 20000){
    int d = idx/200, kk = idx%200;
    int k = (kk<100)? kk : kk-100;
    int j = (kk<100)? d : 100+d;
    Wpt[idx] = aW[k*TDIM + j] * scale0[j];
  } else if (idx < 30000){
    int i2 = idx - 20000;
    int d = i2/100, k = i2%100;
    Wrelt[i2] = aW[k*TDIM + 200 + d] * scale0[200+d];
  }
}

// ---- bp[k] = a_b[k] + sum_j aW[k][j]*shift0[j] ----
__global__ void k_bp(const float* __restrict__ aW, const float* __restrict__ ab,
                     const float* __restrict__ shift0, float* __restrict__ bp){
  int k = blockIdx.x;
  int l = threadIdx.x;            // 64
  float s=0.f;
  for (int j=l;j<TDIM;j+=64) s += aW[k*TDIM+j] * shift0[j];
  #pragma unroll
  for (int m=32;m>=1;m>>=1) s += __shfl_xor(s, m, 64);
  if (l==0) bp[k] = s + ab[k];
}

// ---- V[r][k] = sum_d Wrelt[d][k] * rel[r][d] ----
__global__ void k_V(const float* __restrict__ rel, const float* __restrict__ Wrelt, float* __restrict__ V){
  __shared__ float rf[DIM];
  int r = blockIdx.x;
  int k = threadIdx.x;            // 128
  if (k < DIM) rf[k] = rel[r*DIM+k];
  __syncthreads();
  if (k >= DIM) return;
  float s=0.f;
  for (int d=0;d<DIM;d++) s += Wrelt[d*DIM+k]*rf[d];
  V[r*DIM+k] = s;
}

// ---- UE[n][kk]: per-entity projections, interleaved U0 (kk<100) | U1 (kk>=100), bf16 ----
__global__ __launch_bounds__(256) void k_U(const float* __restrict__ ent, const float* __restrict__ Wpt,
                                           u16* __restrict__ UE){
  __shared__ float sh[DIM][36];   // [d][n], padded
  int n0 = blockIdx.x*32;         // 3125*32 = 100000 exactly
  for (int idx=threadIdx.x; idx<32*DIM; idx+=256){
    int n = idx/DIM, d = idx%DIM;
    sh[d][n] = ent[(size_t)(n0+n)*DIM + d];
  }
  __syncthreads();
  int kk = threadIdx.x;
  if (kk >= 200) return;
  float acc[32];
  #pragma unroll
  for (int i=0;i<32;i++) acc[i]=0.f;
  for (int d=0;d<DIM;d++){
    float w = Wpt[d*200+kk];
    #pragma unroll
    for (int i=0;i<32;i++) acc[i] += w*sh[d][i];
  }
  for (int i=0;i<32;i++) UE[(size_t)(n0+i)*200 + kk] = f2bf(acc[i]);
}

// ---- pass 2a: Sc, Sc2 over all 2E rows of c_pre ----
__global__ __launch_bounds__(256) void k_cstats(const int* __restrict__ trip,
    const u16* __restrict__ UE,
    const float* __restrict__ V, const float* __restrict__ bp,
    float* __restrict__ Sc, float* __restrict__ Sc2){
  __shared__ float scB[DIM], sc2B[DIM];
  for (int i=threadIdx.x;i<DIM;i+=256){ scB[i]=0.f; sc2B[i]=0.f; }
  __syncthreads();
  int lane = threadIdx.x & 31;
  int slot = (blockIdx.x*256 + threadIdx.x) >> 5;
  int nslots = gridDim.x*8;
  bool act = lane < 25;           // 25 lanes * 4 dims = 100
  int dbase = lane*4;
  float bpv[4]={0,0,0,0};
  if (act) ld4f(bp+dbase, bpv);
  float sc[4]={0,0,0,0}, sc2[4]={0,0,0,0};
  for (int e=slot; e<E_EDGES; e+=nslots){
    int3 t = ((const int3*)trip)[e];
    if (act){
      const u16* rx = UE + (size_t)t.x*200;
      const u16* ry = UE + (size_t)t.y*200;
      float A[4],B[4],Ap[4],Bp[4],Vv[4];
      ld4a(rx+dbase, A);        // U0[t0]
      ld4a(ry+100+dbase, B);    // U1[t1]
      ld4a(ry+dbase, Ap);       // U0[t1]
      ld4a(rx+100+dbase, Bp);   // U1[t0]
      ld4f(V+(size_t)t.z*DIM+dbase, Vv);
      #pragma unroll
      for (int i=0;i<4;i++){
        float cf = A[i]+B[i]+Vv[i]+bpv[i];
        float ci = Ap[i]+Bp[i]-Vv[i]+bpv[i];
        sc[i]  += cf+ci;
        sc2[i] += cf*cf + ci*ci;
      }
    }
  }
  if (act){
    #pragma unroll
    for (int i=0;i<4;i++){ atomicAdd(&scB[dbase+i], sc[i]); atomicAdd(&sc2B[dbase+i], sc2[i]); }
  }
  __syncthreads();
  for (int i=threadIdx.x;i<DIM;i+=256){ atomicAdd(&Sc[i], scB[i]); atomicAdd(&Sc2[i], sc2B[i]); }
}

__global__ void k_bn1(const float* __restrict__ g1, const float* __restrict__ b1,
                      const float* __restrict__ Sc, const float* __restrict__ Sc2,
                      float* __restrict__ scale1, float* __restrict__ shift1){
  int k = threadIdx.x;            // 128
  if (k >= DIM) return;
  float mean = Sc[k]*(1.0f/TWO_E);
  float var  = Sc2[k]*(1.0f/TWO_E) - mean*mean;
  float s = g1[k] * rsqrtf(var + BN_EPS);
  scale1[k] = s;
  shift1[k] = b1[k] - mean*s;
}

// ---- pass 2b: attention + segment scatter ----
__global__ __launch_bounds__(256) void k_scatter(const int* __restrict__ trip,
    const u16* __restrict__ UE,
    const float* __restrict__ V, const float* __restrict__ bp,
    const float* __restrict__ scale1, const float* __restrict__ shift1,
    const float* __restrict__ a2W, const float* __restrict__ a2b,
    float* __restrict__ hs, float* __restrict__ ebs, float* __restrict__ relacc){
  int lane = threadIdx.x & 31;
  int slot = (blockIdx.x*256 + threadIdx.x) >> 5;
  int nslots = gridDim.x*8;
  bool act = lane < 25;
  int dbase = lane*4;
  float bpv[4]={0,0,0,0}, s1v[4]={0,0,0,0}, s0v[4]={0,0,0,0}, a2v[4]={0,0,0,0};
  if (act){
    ld4f(bp+dbase, bpv);
    ld4f(scale1+dbase, s1v);
    ld4f(shift1+dbase, s0v);
    ld4f(a2W+dbase, a2v);
  }
  float a2bias = a2b[0];
  float* racc = relacc + (size_t)(blockIdx.x & (REL_COPIES-1))*RELSTRIDE;
  for (int e=slot; e<E_EDGES; e+=nslots){
    int3 t = ((const int3*)trip)[e];
    float cf[4]={0,0,0,0}, ci[4]={0,0,0,0};
    if (act){
      const u16* rx = UE + (size_t)t.x*200;
      const u16* ry = UE + (size_t)t.y*200;
      float A[4],B[4],Ap[4],Bp[4],Vv[4];
      ld4a(rx+dbase, A);        // U0[t0]
      ld4a(ry+100+dbase, B);    // U1[t1]
      ld4a(ry+dbase, Ap);       // U0[t1]
      ld4a(rx+100+dbase, Bp);   // U1[t0]
      ld4f(V+(size_t)t.z*DIM+dbase, Vv);
      #pragma unroll
      for (int i=0;i<4;i++){
        cf[i] = (A[i]+B[i]+Vv[i]+bpv[i])*s1v[i] + s0v[i];
        ci[i] = (Ap[i]+Bp[i]-Vv[i]+bpv[i])*s1v[i] + s0v[i];
      }
    }
    float tf = cf[0]*a2v[0]+cf[1]*a2v[1]+cf[2]*a2v[2]+cf[3]*a2v[3];
    float ti = ci[0]*a2v[0]+ci[1]*a2v[1]+ci[2]*a2v[2]+ci[3]*a2v[3];
    #pragma unroll
    for (int m=16;m>=1;m>>=1){ tf += __shfl_xor(tf,m,32); ti += __shfl_xor(ti,m,32); }
    tf += a2bias; ti += a2bias;
    float ef = expf( tf>0.f ? -tf : -0.01f*tf );   // exp(-leaky_relu(t))
    float ei = expf( ti>0.f ? -ti : -0.01f*ti );
    if (act){
      float* h0 = hs + (size_t)t.x*DIM + dbase;
      float* h1 = hs + (size_t)t.y*DIM + dbase;
      float* rp = racc + t.z*DIM + dbase;
      #pragma unroll
      for (int i=0;i<4;i++){
        float pf = ef*cf[i];
        float pi = ei*ci[i];
        atomicAdd(h0+i, pf);
        atomicAdd(h1+i, pi);
        atomicAdd(rp+i, pf-pi);
      }
    }
    if (lane==0){
      atomicAdd(&ebs[t.x], ef);
      atomicAdd(&ebs[t.y], ei);
    }
  }
}

// ---- finalize h_ent ----
__global__ void k_out_ent(const float* __restrict__ hs, const float* __restrict__ ebs, float* __restrict__ out){
  int idx = blockIdx.x*256 + threadIdx.x;
  if (idx >= NENT*DIM/4) return;
  int base = idx*4;
  int n = base/DIM;
  float eb = ebs[n];
  eb = (eb==0.0f)? 1e-12f : eb;
  float4 h = *(const float4*)(hs+base);
  float v0 = h.x/eb, v1 = h.y/eb, v2 = h.z/eb, v3 = h.w/eb;
  v0 = v0>0.f? v0 : expf(v0)-1.f;
  v1 = v1>0.f? v1 : expf(v1)-1.f;
  v2 = v2>0.f? v2 : expf(v2)-1.f;
  v3 = v3>0.f? v3 : expf(v3)-1.f;
  float4 o = make_float4(v0,v1,v2,v3);
  *(float4*)(out+base) = o;
}

// ---- finalize h_rel ----
__global__ void k_out_rel(const float* __restrict__ relacc, const float* __restrict__ relcnt, float* __restrict__ out){
  int idx = blockIdx.x*256 + threadIdx.x;
  if (idx >= NREL*DIM) return;
  int r = idx/DIM;
  float s = 0.f;
  #pragma unroll
  for (int c=0;c<REL_COPIES;c++) s += relacc[(size_t)c*RELSTRIDE + idx];
  float cn = relcnt[r]; if (cn < 1.f) cn = 1.f;
  float v = s/cn;
  v = v>0.f ? v : expf(v)-1.f;
  out[(size_t)NENT*DIM + idx] = v;
}

extern "C" void kernel_launch(void* const* d_in, const int* in_sizes, int n_in,
                              void* d_out, int out_size, void* d_ws, size_t ws_size,
                              hipStream_t stream){
  const int*   trip = (const int*)d_in[0];
  const float* ent  = (const float*)d_in[1];
  const float* rel  = (const float*)d_in[2];
  const float* aW   = (const float*)d_in[3];
  const float* ab   = (const float*)d_in[4];
  const float* a2W  = (const float*)d_in[5];
  const float* a2b  = (const float*)d_in[6];
  const float* g0   = (const float*)d_in[7];
  const float* b0   = (const float*)d_in[8];
  const float* g1   = (const float*)d_in[9];
  const float* b1   = (const float*)d_in[10];
  float* out = (float*)d_out;
  float* wsf = (float*)d_ws;
  if (ws_size < TOTAL_F*sizeof(float)) return;   // insufficient scratch
  u16* UE = (u16*)(wsf + OFF_U);

  hipMemsetAsync(d_ws, 0, ZERO_END*sizeof(float), stream);

  k_hist<<<dim3((E_EDGES+255)/256), dim3(256), 0, stream>>>(trip, wsf+OFF_DEG, wsf+OFF_RELCNT);
  k_entstats<<<dim3((NENT+255)/256), dim3(128), 0, stream>>>(ent, wsf+OFF_DEG, wsf+OFF_S1, wsf+OFF_S2);
  k_relstats<<<dim3(1), dim3(128), 0, stream>>>(rel, wsf+OFF_RELCNT, wsf+OFF_S2R);
  k_scale0<<<dim3(1), dim3(320), 0, stream>>>(g0, b0, wsf+OFF_S1, wsf+OFF_S2, wsf+OFF_S2R,
                                              wsf+OFF_SCALE0, wsf+OFF_SHIFT0);
  k_foldW<<<dim3(118), dim3(256), 0, stream>>>(aW, wsf+OFF_SCALE0, wsf+OFF_WPT, wsf+OFF_WRELT);
  k_bp<<<dim3(100), dim3(64), 0, stream>>>(aW, ab, wsf+OFF_SHIFT0, wsf+OFF_BP);
  k_V<<<dim3(NREL), dim3(128), 0, stream>>>(rel, wsf+OFF_WRELT, wsf+OFF_V);
  k_U<<<dim3(NENT/32), dim3(256), 0, stream>>>(ent, wsf+OFF_WPT, UE);
  k_cstats<<<dim3(2048), dim3(256), 0, stream>>>(trip, UE, wsf+OFF_V, wsf+OFF_BP,
                                                 wsf+OFF_SC, wsf+OFF_SC2);
  k_bn1<<<dim3(1), dim3(128), 0, stream>>>(g1, b1, wsf+OFF_SC, wsf+OFF_SC2,
                                           wsf+OFF_SCALE1, wsf+OFF_SHIFT1);
  k_scatter<<<dim3(2048), dim3(256), 0, stream>>>(trip, UE, wsf+OFF_V, wsf+OFF_BP,
                                                  wsf+OFF_SCALE1, wsf+OFF_SHIFT1, a2W, a2b,
                                                  wsf+OFF_HS, wsf+OFF_EBS, wsf+OFF_RELACC);
  k_out_ent<<<dim3((NENT*DIM/4+255)/256), dim3(256), 0, stream>>>(wsf+OFF_HS, wsf+OFF_EBS, out);
  k_out_rel<<<dim3((NREL*DIM+255)/256), dim3(256), 0, stream>>>(wsf+OFF_RELACC, wsf+OFF_RELCNT, out);
}

// Round 3
// 1546.377 us; speedup vs baseline: 1.8758x; 1.8758x over previous
//
#include <hip/hip_runtime.h>
#include <hip/hip_bf16.h>

#define E_EDGES 500000
#define NENT    100000
#define NREL    237
#define DIM     100
#define TDIM    300
#define TWO_E   1000000
#define BN_EPS  1e-5f
#define PITCH   256        // u16 elems per UEp row (512B): U0 at +0, U1 at +128

typedef unsigned short u16;
typedef unsigned int   u32;

// ---------- ws layout (offsets in floats) ----------
static const size_t OFF_DEG     = 0;         // 100000 (zeroed)
static const size_t OFF_RELCNT  = 100000;    // 256    (zeroed)
static const size_t OFF_OFFS    = 100256;    // u32[100001] (written by scan)
static const size_t OFF_CUR     = 200608;    // u32[100000] (zeroed)
static const size_t OFF_ROFF    = 300608;    // u32[238]
static const size_t OFF_RCUR    = 300864;    // u32[256] (zeroed)
static const size_t OFF_S1      = 301120;    // 128 (zeroed)
static const size_t OFF_S2      = 301248;    // 128 (zeroed)
static const size_t OFF_S2R     = 301376;    // 128 (zeroed)
static const size_t OFF_SC      = 301504;    // 128 (zeroed)
static const size_t OFF_SC2     = 301632;    // 128 (zeroed)
static const size_t OFF_CONST   = 301760;    // 64  (zeroed)
static const size_t ZERO_END    = 301824;
static const size_t OFF_SCALE0  = 301824;    // 320
static const size_t OFF_SHIFT0  = 302144;    // 320
static const size_t OFF_BP      = 302464;    // 128
static const size_t OFF_SCALE1  = 302592;    // 128
static const size_t OFF_SHIFT1  = 302720;    // 128
static const size_t OFF_WVEC    = 302848;    // 128
static const size_t OFF_WPT     = 302976;    // 100*200
static const size_t OFF_WRELT   = 322976;    // 100*100
static const size_t OFF_V       = 332976;    // 237*100 (pitch 100 f32)
static const size_t OFF_PSI     = 356720;    // 256
static const size_t OFF_PHI0    = 356976;    // 100000
static const size_t OFF_PHI1    = 456976;    // 100000
static const size_t OFF_INC     = 556976;    // u32[1000000]
static const size_t OFF_RELEDGE = 1556976;   // u32[500000]
static const size_t OFF_UE      = 2056976;   // u16[100000*256] = 12.8M floats
static const size_t TOTAL_F     = 14856976;  // ~59.4 MB

__device__ __forceinline__ float bf2f(u16 u){ return __uint_as_float(((u32)u)<<16); }
__device__ __forceinline__ u16 f2bf(float f){
  u32 x = __float_as_uint(f);
  x += 0x7FFFu + ((x>>16)&1u);
  return (u16)(x>>16);
}
__device__ __forceinline__ void ld4a(const u16* p, float* o){
  ushort4 u = *(const ushort4*)p;
  o[0]=bf2f(u.x); o[1]=bf2f(u.y); o[2]=bf2f(u.z); o[3]=bf2f(u.w);
}
__device__ __forceinline__ void ld4f(const float* p, float* o){
  float4 v = *(const float4*)p;
  o[0]=v.x; o[1]=v.y; o[2]=v.z; o[3]=v.w;
}
__device__ __forceinline__ float eluf(float v){ return v>0.f ? v : expf(v)-1.f; }
__device__ __forceinline__ float ewt(float t){ return expf( t>0.f ? -t : -0.01f*t ); }

// ---- histograms ----
__global__ void k_hist(const int* __restrict__ trip, float* __restrict__ deg, float* __restrict__ relcnt){
  int e = blockIdx.x*256 + threadIdx.x;
  if (e >= E_EDGES) return;
  int3 t = ((const int3*)trip)[e];
  atomicAdd(&deg[t.x], 1.0f);
  atomicAdd(&deg[t.y], 1.0f);
  atomicAdd(&relcnt[t.z], 1.0f);
}

// ---- bn0 entity-column stats (degree-weighted) ----
__global__ void k_entstats(const float* __restrict__ ent, const float* __restrict__ deg,
                           float* __restrict__ S1, float* __restrict__ S2){
  int d = threadIdx.x;            // 128, d<100 active
  if (d >= DIM) return;
  int n0 = blockIdx.x*256;
  int nend = n0+256; if (nend > NENT) nend = NENT;
  float s1=0.f, s2=0.f;
  for (int n=n0;n<nend;n++){
    float w = deg[n];
    float x = ent[(size_t)n*DIM + d];
    s1 += w*x; s2 += w*x*x;
  }
  atomicAdd(&S1[d], s1);
  atomicAdd(&S2[d], s2);
}

__global__ void k_relstats(const float* __restrict__ rel, const float* __restrict__ relcnt, float* __restrict__ S2r){
  int d = threadIdx.x;
  if (d >= DIM) return;
  float s=0.f;
  for (int r=0;r<NREL;r++){
    float x = rel[r*DIM+d];
    s += relcnt[r]*x*x;
  }
  S2r[d] = s;
}

__global__ void k_scale0(const float* __restrict__ g0, const float* __restrict__ b0,
                         const float* __restrict__ S1, const float* __restrict__ S2, const float* __restrict__ S2r,
                         float* __restrict__ scale0, float* __restrict__ shift0){
  int j = threadIdx.x;            // 320
  if (j >= TDIM) return;
  float mean, var;
  if (j < 200){
    int d = (j<100)? j : j-100;
    mean = S1[d] * (1.0f/TWO_E);
    var  = S2[d] * (1.0f/TWO_E) - mean*mean;
  } else {
    mean = 0.0f;
    var  = S2r[j-200] * (1.0f/E_EDGES);
  }
  float sc = g0[j] * rsqrtf(var + BN_EPS);
  scale0[j] = sc;
  shift0[j] = b0[j] - mean*sc;
}

__global__ void k_foldW(const float* __restrict__ aW, const float* __restrict__ scale0,
                        float* __restrict__ Wpt, float* __restrict__ Wrelt){
  int idx = blockIdx.x*256 + threadIdx.x;
  if (idx < 20000){
    int d = idx/200, kk = idx%200;
    int k = (kk<100)? kk : kk-100;
    int j = (kk<100)? d : 100+d;
    Wpt[idx] = aW[k*TDIM + j] * scale0[j];
  } else if (idx < 30000){
    int i2 = idx - 20000;
    int d = i2/100, k = i2%100;
    Wrelt[i2] = aW[k*TDIM + 200 + d] * scale0[200+d];
  }
}

__global__ void k_bp(const float* __restrict__ aW, const float* __restrict__ ab,
                     const float* __restrict__ shift0, float* __restrict__ bp){
  int k = blockIdx.x;
  int l = threadIdx.x;            // 64
  float s=0.f;
  for (int j=l;j<TDIM;j+=64) s += aW[k*TDIM+j] * shift0[j];
  #pragma unroll
  for (int m=32;m>=1;m>>=1) s += __shfl_xor(s, m, 64);
  if (l==0) bp[k] = s + ab[k];
}

__global__ void k_V(const float* __restrict__ rel, const float* __restrict__ Wrelt, float* __restrict__ V){
  __shared__ float rf[DIM];
  int r = blockIdx.x;
  int k = threadIdx.x;            // 128
  if (k < DIM) rf[k] = rel[r*DIM+k];
  __syncthreads();
  if (k >= DIM) return;
  float s=0.f;
  for (int d=0;d<DIM;d++) s += Wrelt[d*DIM+k]*rf[d];
  V[r*DIM+k] = s;
}

// ---- UEp[n][256] bf16: U0 at col 0..99, U1 at col 128..227 ----
__global__ __launch_bounds__(256) void k_U(const float* __restrict__ ent, const float* __restrict__ Wpt,
                                           u16* __restrict__ UEp){
  __shared__ float sh[DIM][36];
  int n0 = blockIdx.x*32;         // 3125*32 = 100000
  for (int idx=threadIdx.x; idx<32*DIM; idx+=256){
    int n = idx/DIM, d = idx%DIM;
    sh[d][n] = ent[(size_t)(n0+n)*DIM + d];
  }
  __syncthreads();
  int kk = threadIdx.x;
  if (kk >= 200) return;
  float acc[32];
  #pragma unroll
  for (int i=0;i<32;i++) acc[i]=0.f;
  for (int d=0;d<DIM;d++){
    float w = Wpt[d*200+kk];
    #pragma unroll
    for (int i=0;i<32;i++) acc[i] += w*sh[d][i];
  }
  int col = (kk<100)? kk : (28+kk);   // 128 + (kk-100)
  for (int i=0;i<32;i++) UEp[(size_t)(n0+i)*PITCH + col] = f2bf(acc[i]);
}

// ---- CSR offsets: exclusive scan of deg (single block) + rel offsets ----
__global__ void k_scan(const float* __restrict__ deg, const float* __restrict__ relcnt,
                       u32* __restrict__ offs, u32* __restrict__ roff){
  __shared__ u32 part[256];
  __shared__ u32 base[256];
  int t = threadIdx.x;
  int c0 = t*391, c1 = c0+391; if (c1 > NENT) c1 = NENT; if (c0 > NENT) c0 = NENT;
  u32 s=0;
  for (int n=c0;n<c1;n++) s += (u32)deg[n];
  part[t]=s; __syncthreads();
  if (t==0){ u32 run=0; for (int i=0;i<256;i++){ base[i]=run; run+=part[i]; } }
  __syncthreads();
  u32 run = base[t];
  for (int n=c0;n<c1;n++){ offs[n]=run; run += (u32)deg[n]; }
  if (t==255) offs[NENT] = run;
  if (t==0){ u32 r=0; for (int i=0;i<NREL;i++){ roff[i]=r; r+=(u32)relcnt[i]; } roff[NREL]=r; }
}

// ---- fill incidence lists ----
__global__ void k_inc(const int* __restrict__ trip, const u32* __restrict__ offs, u32* __restrict__ cur,
                      const u32* __restrict__ roff, u32* __restrict__ rcur,
                      u32* __restrict__ inc, u32* __restrict__ reledge){
  int e = blockIdx.x*256 + threadIdx.x;
  if (e >= E_EDGES) return;
  int3 t = ((const int3*)trip)[e];
  u32 p0 = offs[t.x] + atomicAdd(&cur[t.x], 1u);
  inc[p0] = (u32)t.y | ((u32)t.z<<17);
  u32 p1 = offs[t.y] + atomicAdd(&cur[t.y], 1u);
  inc[p1] = (u32)t.x | ((u32)t.z<<17) | (1u<<25);
  u32 q = roff[t.z] + atomicAdd(&rcur[t.z], 1u);
  reledge[q] = (u32)e;
}

// ---- bn1 stats over 2E rows of c_pre (edge sweep, 4 row gathers) ----
__global__ __launch_bounds__(256) void k_cstats(const int* __restrict__ trip,
    const u16* __restrict__ UEp, const float* __restrict__ V, const float* __restrict__ bp,
    float* __restrict__ Sc, float* __restrict__ Sc2){
  __shared__ float scB[DIM], sc2B[DIM];
  for (int i=threadIdx.x;i<DIM;i+=256){ scB[i]=0.f; sc2B[i]=0.f; }
  __syncthreads();
  int lane = threadIdx.x & 31;
  int slot = (blockIdx.x*256 + threadIdx.x) >> 5;
  int nslots = gridDim.x*8;
  bool act = lane < 25;
  int dbase = lane*4;
  float bpv[4]={0,0,0,0};
  if (act) ld4f(bp+dbase, bpv);
  float sc[4]={0,0,0,0}, sc2[4]={0,0,0,0};
  for (int e=slot; e<E_EDGES; e+=nslots){
    int3 t = ((const int3*)trip)[e];
    if (act){
      const u16* rx = UEp + (size_t)t.x*PITCH;
      const u16* ry = UEp + (size_t)t.y*PITCH;
      float P[4],Q[4],R[4],S[4],Vv[4];
      ld4a(rx+dbase, P);          // U0[t0]
      ld4a(ry+128+dbase, Q);      // U1[t1]
      ld4a(ry+dbase, R);          // U0[t1]
      ld4a(rx+128+dbase, S);      // U1[t0]
      ld4f(V+(size_t)t.z*DIM+dbase, Vv);
      #pragma unroll
      for (int i=0;i<4;i++){
        float cf = P[i]+Q[i]+Vv[i]+bpv[i];
        float ci = R[i]+S[i]-Vv[i]+bpv[i];
        sc[i]  += cf+ci;
        sc2[i] += cf*cf + ci*ci;
      }
    }
  }
  if (act){
    #pragma unroll
    for (int i=0;i<4;i++){ atomicAdd(&scB[dbase+i], sc[i]); atomicAdd(&sc2B[dbase+i], sc2[i]); }
  }
  __syncthreads();
  for (int i=threadIdx.x;i<DIM;i+=256){ atomicAdd(&Sc[i], scB[i]); atomicAdd(&Sc2[i], sc2B[i]); }
}

// ---- bn1 affine + attention vector w + scalar C ----
__global__ void k_bn1x(const float* __restrict__ g1, const float* __restrict__ b1,
                       const float* __restrict__ Sc, const float* __restrict__ Sc2,
                       const float* __restrict__ bp, const float* __restrict__ a2W, const float* __restrict__ a2b,
                       float* __restrict__ scale1, float* __restrict__ shift1,
                       float* __restrict__ wvec, float* __restrict__ consts){
  __shared__ float red[128];
  int k = threadIdx.x;            // 128
  float contrib = 0.f;
  if (k < DIM){
    float mean = Sc[k]*(1.0f/TWO_E);
    float var  = Sc2[k]*(1.0f/TWO_E) - mean*mean;
    float s = g1[k] * rsqrtf(var + BN_EPS);
    float sh = b1[k] - mean*s;
    float a2 = a2W[k];
    scale1[k] = s;
    shift1[k] = sh;
    float wv = s*a2;
    wvec[k] = wv;
    contrib = bp[k]*wv + sh*a2;
  }
  red[k] = contrib;
  __syncthreads();
  for (int m=64;m>=1;m>>=1){ if (k<m) red[k]+=red[k+m]; __syncthreads(); }
  if (k==0) consts[0] = red[0] + a2b[0];
}

// ---- phi0[n]=U0[n].w, phi1[n]=U1[n].w ----
__global__ __launch_bounds__(256) void k_phi(const u16* __restrict__ UEp, const float* __restrict__ wvec,
                                             float* __restrict__ phi0, float* __restrict__ phi1){
  int lane = threadIdx.x & 31;
  int n = blockIdx.x*8 + (threadIdx.x>>5);
  bool act = lane < 25;
  int dbase = lane*4;
  float w4[4]={0,0,0,0};
  float p0=0.f, p1=0.f;
  if (act){
    ld4f(wvec+dbase, w4);
    float P[4], Q[4];
    ld4a(UEp + (size_t)n*PITCH + dbase, P);
    ld4a(UEp + (size_t)n*PITCH + 128 + dbase, Q);
    #pragma unroll
    for (int i=0;i<4;i++){ p0 += P[i]*w4[i]; p1 += Q[i]*w4[i]; }
  }
  #pragma unroll
  for (int m=16;m>=1;m>>=1){ p0 += __shfl_xor(p0,m,32); p1 += __shfl_xor(p1,m,32); }
  if (lane==0){ phi0[n]=p0; phi1[n]=p1; }
}

// ---- psi[r]=V[r].w ----
__global__ void k_psi(const float* __restrict__ V, const float* __restrict__ wvec, float* __restrict__ psi){
  __shared__ float w[DIM];
  int t = threadIdx.x;            // 256
  if (t < DIM) w[t] = wvec[t];
  __syncthreads();
  if (t >= NREL) return;
  float s=0.f;
  for (int k=0;k<DIM;k++) s += V[t*DIM+k]*w[k];
  psi[t] = s;
}

// ---- entity aggregation: one 32-lane slot per entity, zero atomics ----
__global__ __launch_bounds__(256) void k_aggr_ent(const u32* __restrict__ offs, const u32* __restrict__ inc,
    const u16* __restrict__ UEp, const float* __restrict__ V,
    const float* __restrict__ phi0, const float* __restrict__ phi1, const float* __restrict__ psi,
    const float* __restrict__ consts, const float* __restrict__ bp,
    const float* __restrict__ scale1, const float* __restrict__ shift1,
    float* __restrict__ out){
  int lane = threadIdx.x & 31;
  int n = blockIdx.x*8 + (threadIdx.x>>5);
  bool act = lane < 25;
  int dbase = lane*4;
  u32 o0 = offs[n], o1 = offs[n+1];
  float C = consts[0];
  float p0n = phi0[n];
  float acc[4]={0,0,0,0};
  float wsum=0.f;
  for (u32 i=o0; i<o1; i++){
    u32 pk = inc[i];
    u32 other = pk & 0x1FFFFu;
    u32 rr = (pk>>17) & 0xFFu;
    bool neg = (pk>>25) != 0u;
    float ps = psi[rr];
    float t = p0n + phi1[other] + (neg ? -ps : ps) + C;
    float w = ewt(t);
    wsum += w;
    if (act){
      float B[4], Vv[4];
      ld4a(UEp + (size_t)other*PITCH + 128 + dbase, B);
      ld4f(V + (size_t)rr*DIM + dbase, Vv);
      float sg = neg ? -1.f : 1.f;
      #pragma unroll
      for (int i2=0;i2<4;i2++) acc[i2] += w*(B[i2]+sg*Vv[i2]);
    }
  }
  if (act){
    float o4[4];
    if (o1 == o0){
      o4[0]=o4[1]=o4[2]=o4[3]=0.f;
    } else {
      float P[4], bp4[4], s14[4], sh4[4];
      ld4a(UEp + (size_t)n*PITCH + dbase, P);
      ld4f(bp+dbase, bp4);
      ld4f(scale1+dbase, s14);
      ld4f(shift1+dbase, sh4);
      float inv = __frcp_rn(wsum);
      #pragma unroll
      for (int i2=0;i2<4;i2++){
        float v = (P[i2]+bp4[i2])*s14[i2] + sh4[i2] + s14[i2]*acc[i2]*inv;
        o4[i2] = eluf(v);
      }
    }
    *(float4*)(out + (size_t)n*DIM + dbase) = make_float4(o4[0],o4[1],o4[2],o4[3]);
  }
}

// ---- rel aggregation: one block per rel, LDS reduce, zero global atomics ----
__global__ __launch_bounds__(256) void k_aggr_rel(const int* __restrict__ trip,
    const u32* __restrict__ roff, const u32* __restrict__ reledge,
    const u16* __restrict__ UEp, const float* __restrict__ V,
    const float* __restrict__ phi0, const float* __restrict__ phi1, const float* __restrict__ psi,
    const float* __restrict__ consts, const float* __restrict__ bp,
    const float* __restrict__ scale1, const float* __restrict__ shift1,
    const float* __restrict__ relcnt, float* __restrict__ out){
  __shared__ float red[8][104];
  int r = blockIdx.x;
  int lane = threadIdx.x & 31;
  int slot = threadIdx.x >> 5;    // 8 slots
  bool act = lane < 25;
  int dbase = lane*4;
  float C = consts[0];
  float psir = psi[r];
  float bp4[4]={0,0,0,0}, s14[4]={0,0,0,0}, sh4[4]={0,0,0,0}, Vv[4]={0,0,0,0};
  if (act){
    ld4f(bp+dbase, bp4);
    ld4f(scale1+dbase, s14);
    ld4f(shift1+dbase, sh4);
    ld4f(V + (size_t)r*DIM + dbase, Vv);
  }
  u32 q0 = roff[r], q1 = roff[r+1];
  float acc[4]={0,0,0,0};
  for (u32 q=q0+slot; q<q1; q+=8){
    int e = (int)reledge[q];
    int3 t = ((const int3*)trip)[e];
    float tf = phi0[t.x] + phi1[t.y] + psir + C;
    float ti = phi0[t.y] + phi1[t.x] - psir + C;
    float ef = ewt(tf);
    float ei = ewt(ti);
    if (act){
      const u16* rx = UEp + (size_t)t.x*PITCH;
      const u16* ry = UEp + (size_t)t.y*PITCH;
      float P[4],Q[4],R[4],S[4];
      ld4a(rx+dbase, P);
      ld4a(ry+128+dbase, Q);
      ld4a(ry+dbase, R);
      ld4a(rx+128+dbase, S);
      #pragma unroll
      for (int i=0;i<4;i++){
        float cf = (P[i]+Q[i]+Vv[i]+bp4[i])*s14[i] + sh4[i];
        float ci = (R[i]+S[i]-Vv[i]+bp4[i])*s14[i] + sh4[i];
        acc[i] += ef*cf - ei*ci;
      }
    }
  }
  if (act){
    #pragma unroll
    for (int i=0;i<4;i++) red[slot][dbase+i] = acc[i];
  }
  __syncthreads();
  int k = threadIdx.x;
  if (k < DIM){
    float s = 0.f;
    #pragma unroll
    for (int sl=0;sl<8;sl++) s += red[sl][k];
    float cn = relcnt[r]; if (cn < 1.f) cn = 1.f;
    out[(size_t)NENT*DIM + (size_t)r*DIM + k] = eluf(s/cn);
  }
}

extern "C" void kernel_launch(void* const* d_in, const int* in_sizes, int n_in,
                              void* d_out, int out_size, void* d_ws, size_t ws_size,
                              hipStream_t stream){
  const int*   trip = (const int*)d_in[0];
  const float* ent  = (const float*)d_in[1];
  const float* rel  = (const float*)d_in[2];
  const float* aW   = (const float*)d_in[3];
  const float* ab   = (const float*)d_in[4];
  const float* a2W  = (const float*)d_in[5];
  const float* a2b  = (const float*)d_in[6];
  const float* g0   = (const float*)d_in[7];
  const float* b0   = (const float*)d_in[8];
  const float* g1   = (const float*)d_in[9];
  const float* b1   = (const float*)d_in[10];
  float* out = (float*)d_out;
  float* wsf = (float*)d_ws;
  if (ws_size < TOTAL_F*sizeof(float)) return;
  u16* UEp  = (u16*)(wsf + OFF_UE);
  u32* offs = (u32*)(wsf + OFF_OFFS);
  u32* cur  = (u32*)(wsf + OFF_CUR);
  u32* roff = (u32*)(wsf + OFF_ROFF);
  u32* rcur = (u32*)(wsf + OFF_RCUR);
  u32* inc  = (u32*)(wsf + OFF_INC);
  u32* rele = (u32*)(wsf + OFF_RELEDGE);

  hipMemsetAsync(d_ws, 0, ZERO_END*sizeof(float), stream);

  k_hist<<<dim3((E_EDGES+255)/256), dim3(256), 0, stream>>>(trip, wsf+OFF_DEG, wsf+OFF_RELCNT);
  k_entstats<<<dim3((NENT+255)/256), dim3(128), 0, stream>>>(ent, wsf+OFF_DEG, wsf+OFF_S1, wsf+OFF_S2);
  k_relstats<<<dim3(1), dim3(128), 0, stream>>>(rel, wsf+OFF_RELCNT, wsf+OFF_S2R);
  k_scale0<<<dim3(1), dim3(320), 0, stream>>>(g0, b0, wsf+OFF_S1, wsf+OFF_S2, wsf+OFF_S2R,
                                              wsf+OFF_SCALE0, wsf+OFF_SHIFT0);
  k_foldW<<<dim3(118), dim3(256), 0, stream>>>(aW, wsf+OFF_SCALE0, wsf+OFF_WPT, wsf+OFF_WRELT);
  k_bp<<<dim3(100), dim3(64), 0, stream>>>(aW, ab, wsf+OFF_SHIFT0, wsf+OFF_BP);
  k_V<<<dim3(NREL), dim3(128), 0, stream>>>(rel, wsf+OFF_WRELT, wsf+OFF_V);
  k_U<<<dim3(NENT/32), dim3(256), 0, stream>>>(ent, wsf+OFF_WPT, UEp);
  k_scan<<<dim3(1), dim3(256), 0, stream>>>(wsf+OFF_DEG, wsf+OFF_RELCNT, offs, roff);
  k_inc<<<dim3((E_EDGES+255)/256), dim3(256), 0, stream>>>(trip, offs, cur, roff, rcur, inc, rele);
  k_cstats<<<dim3(2048), dim3(256), 0, stream>>>(trip, UEp, wsf+OFF_V, wsf+OFF_BP,
                                                 wsf+OFF_SC, wsf+OFF_SC2);
  k_bn1x<<<dim3(1), dim3(128), 0, stream>>>(g1, b1, wsf+OFF_SC, wsf+OFF_SC2, wsf+OFF_BP, a2W, a2b,
                                            wsf+OFF_SCALE1, wsf+OFF_SHIFT1, wsf+OFF_WVEC, wsf+OFF_CONST);
  k_phi<<<dim3(NENT/8), dim3(256), 0, stream>>>(UEp, wsf+OFF_WVEC, wsf+OFF_PHI0, wsf+OFF_PHI1);
  k_psi<<<dim3(1), dim3(256), 0, stream>>>(wsf+OFF_V, wsf+OFF_WVEC, wsf+OFF_PSI);
  k_aggr_ent<<<dim3(NENT/8), dim3(256), 0, stream>>>(offs, inc, UEp, wsf+OFF_V,
                                                     wsf+OFF_PHI0, wsf+OFF_PHI1, wsf+OFF_PSI,
                                                     wsf+OFF_CONST, wsf+OFF_BP,
                                                     wsf+OFF_SCALE1, wsf+OFF_SHIFT1, out);
  k_aggr_rel<<<dim3(NREL), dim3(256), 0, stream>>>(trip, roff, rele, UEp, wsf+OFF_V,
                                                   wsf+OFF_PHI0, wsf+OFF_PHI1, wsf+OFF_PSI,
                                                   wsf+OFF_CONST, wsf+OFF_BP,
                                                   wsf+OFF_SCALE1, wsf+OFF_SHIFT1,
                                                   wsf+OFF_RELCNT, out);
}

// Round 4
// 1028.840 us; speedup vs baseline: 2.8193x; 1.5030x over previous
//
#include <hip/hip_runtime.h>
#include <hip/hip_bf16.h>

#define E_EDGES 500000
#define NENT    100000
#define NREL    237
#define DIM     100
#define TDIM    300
#define TWO_E   1000000
#define BN_EPS  1e-5f
#define PITCH   256        // u16 elems per UEp row (512B): U0 at +0, U1 at +128
#define NB      512        // histogram/scatter blocks
#define CHUNK   977        // ceil(E_EDGES/NB)

typedef unsigned short u16;
typedef unsigned int   u32;

// ---------- ws layout (offsets in floats) ----------
static const size_t OFF_DEG     = 0;         // u32[100000] (zeroed)
static const size_t OFF_CUR     = 100000;    // u32[100000] (zeroed)
static const size_t OFF_S1      = 200000;    // 128 (zeroed)
static const size_t OFF_S2      = 200128;    // 128 (zeroed)
static const size_t OFF_S2R     = 200256;    // 128 (zeroed)
static const size_t OFF_SC      = 200384;    // 128 (zeroed)
static const size_t OFF_SC2     = 200512;    // 128 (zeroed)
static const size_t OFF_CONST   = 200640;    // 64  (zeroed)
static const size_t ZERO_END    = 200704;
static const size_t OFF_OFFS    = 200704;    // u32[100001]
static const size_t OFF_ROFF    = 300720;    // u32[240]
static const size_t OFF_RELCNTF = 300960;    // float[256]
static const size_t OFF_BHIST   = 301216;    // u32[NB*256]
static const size_t OFF_RBASE   = 432288;    // u32[237*NB]
static const size_t OFF_SCALE0  = 553632;    // 320
static const size_t OFF_SHIFT0  = 553952;    // 320
static const size_t OFF_BP      = 554272;    // 128
static const size_t OFF_SCALE1  = 554400;    // 128
static const size_t OFF_SHIFT1  = 554528;    // 128
static const size_t OFF_WVEC    = 554656;    // 128
static const size_t OFF_WPT     = 554784;    // 100*200
static const size_t OFF_WRELT   = 574784;    // 100*100
static const size_t OFF_V       = 584784;    // 237*100 (pitch 100 f32)
static const size_t OFF_PSI     = 608528;    // 256
static const size_t OFF_PHI0    = 608784;    // 100000
static const size_t OFF_PHI1    = 708784;    // 100000
static const size_t OFF_INC     = 808784;    // u32[1000000]
static const size_t OFF_RELEDGE = 1808784;   // u32[500000]
static const size_t OFF_UE      = 2308784;   // u16[100000*256] = 12.8M floats
static const size_t TOTAL_F     = 15108784;  // ~60.4 MB

__device__ __forceinline__ float bf2f(u16 u){ return __uint_as_float(((u32)u)<<16); }
__device__ __forceinline__ u16 f2bf(float f){
  u32 x = __float_as_uint(f);
  x += 0x7FFFu + ((x>>16)&1u);
  return (u16)(x>>16);
}
__device__ __forceinline__ void ld4a(const u16* p, float* o){
  ushort4 u = *(const ushort4*)p;
  o[0]=bf2f(u.x); o[1]=bf2f(u.y); o[2]=bf2f(u.z); o[3]=bf2f(u.w);
}
__device__ __forceinline__ void ld4f(const float* p, float* o){
  float4 v = *(const float4*)p;
  o[0]=v.x; o[1]=v.y; o[2]=v.z; o[3]=v.w;
}
__device__ __forceinline__ float eluf(float v){ return v>0.f ? v : expf(v)-1.f; }
__device__ __forceinline__ float ewt(float t){ return expf( t>0.f ? -t : -0.01f*t ); }

// ---- pass A: deg atomics (spread) + per-block rel histogram in LDS ----
__global__ __launch_bounds__(256) void k_histA(const int* __restrict__ trip,
                                               u32* __restrict__ deg, u32* __restrict__ bhist){
  __shared__ u32 lh[256];
  int t = threadIdx.x, b = blockIdx.x;
  lh[t] = 0u;
  __syncthreads();
  int e0 = b*CHUNK, e1 = e0+CHUNK; if (e1 > E_EDGES) e1 = E_EDGES;
  for (int e=e0+t; e<e1; e+=256){
    int3 tr = ((const int3*)trip)[e];
    atomicAdd(&deg[tr.x], 1u);
    atomicAdd(&deg[tr.y], 1u);
    atomicAdd(&lh[tr.z], 1u);
  }
  __syncthreads();
  bhist[b*256 + t] = lh[t];
}

// ---- scan: entity CSR offsets + rel per-block bases (deterministic, no atomics) ----
__global__ void k_scan(const u32* __restrict__ deg, const u32* __restrict__ bhist,
                       u32* __restrict__ offs, u32* __restrict__ roff,
                       u32* __restrict__ rbase, float* __restrict__ relcntf){
  __shared__ u32 part[256];
  __shared__ u32 base[256];
  __shared__ u32 rtot[256];
  int t = threadIdx.x;
  // entity offsets
  int c0 = t*391, c1 = c0+391; if (c1 > NENT) c1 = NENT; if (c0 > NENT) c0 = NENT;
  u32 s=0;
  for (int n=c0;n<c1;n++) s += deg[n];
  part[t]=s; __syncthreads();
  if (t==0){ u32 run=0; for (int i=0;i<256;i++){ base[i]=run; run+=part[i]; } }
  __syncthreads();
  u32 run = base[t];
  for (int n=c0;n<c1;n++){ offs[n]=run; run += deg[n]; }
  if (t==255) offs[NENT] = run;
  // rel per-block bases
  u32 rr=0;
  if (t < NREL){
    for (int b=0;b<NB;b++){ rbase[t*NB+b]=rr; rr += bhist[b*256+t]; }
  }
  rtot[t]=rr;
  __syncthreads();
  if (t==0){
    u32 r=0;
    for (int i=0;i<NREL;i++){ roff[i]=r; relcntf[i]=(float)rtot[i]; r+=rtot[i]; }
    roff[NREL]=r;
  }
}

// ---- pass B: fill incidence lists (rel part atomic-free) ----
__global__ __launch_bounds__(256) void k_incB(const int* __restrict__ trip,
                      const u32* __restrict__ offs, u32* __restrict__ cur,
                      const u32* __restrict__ roff, const u32* __restrict__ rbase,
                      u32* __restrict__ inc, u32* __restrict__ reledge){
  __shared__ u32 lh[256];
  int t = threadIdx.x, b = blockIdx.x;
  lh[t] = 0u;
  __syncthreads();
  int e0 = b*CHUNK, e1 = e0+CHUNK; if (e1 > E_EDGES) e1 = E_EDGES;
  for (int e=e0+t; e<e1; e+=256){
    int3 tr = ((const int3*)trip)[e];
    u32 p0 = offs[tr.x] + atomicAdd(&cur[tr.x], 1u);
    inc[p0] = (u32)tr.y | ((u32)tr.z<<17);
    u32 p1 = offs[tr.y] + atomicAdd(&cur[tr.y], 1u);
    inc[p1] = (u32)tr.x | ((u32)tr.z<<17) | (1u<<25);
    u32 loff = atomicAdd(&lh[tr.z], 1u);
    reledge[roff[tr.z] + rbase[(u32)tr.z*NB + b] + loff] = (u32)e;
  }
}

// ---- bn0 entity-column stats (degree-weighted) ----
__global__ void k_entstats(const float* __restrict__ ent, const u32* __restrict__ deg,
                           float* __restrict__ S1, float* __restrict__ S2){
  int d = threadIdx.x;            // 128, d<100 active
  if (d >= DIM) return;
  int n0 = blockIdx.x*256;
  int nend = n0+256; if (nend > NENT) nend = NENT;
  float s1=0.f, s2=0.f;
  for (int n=n0;n<nend;n++){
    float w = (float)deg[n];
    float x = ent[(size_t)n*DIM + d];
    s1 += w*x; s2 += w*x*x;
  }
  atomicAdd(&S1[d], s1);
  atomicAdd(&S2[d], s2);
}

__global__ void k_relstats(const float* __restrict__ rel, const float* __restrict__ relcnt, float* __restrict__ S2r){
  int d = threadIdx.x;
  if (d >= DIM) return;
  float s=0.f;
  for (int r=0;r<NREL;r++){
    float x = rel[r*DIM+d];
    s += relcnt[r]*x*x;
  }
  S2r[d] = s;
}

__global__ void k_scale0(const float* __restrict__ g0, const float* __restrict__ b0,
                         const float* __restrict__ S1, const float* __restrict__ S2, const float* __restrict__ S2r,
                         float* __restrict__ scale0, float* __restrict__ shift0){
  int j = threadIdx.x;            // 320
  if (j >= TDIM) return;
  float mean, var;
  if (j < 200){
    int d = (j<100)? j : j-100;
    mean = S1[d] * (1.0f/TWO_E);
    var  = S2[d] * (1.0f/TWO_E) - mean*mean;
  } else {
    mean = 0.0f;
    var  = S2r[j-200] * (1.0f/E_EDGES);
  }
  float sc = g0[j] * rsqrtf(var + BN_EPS);
  scale0[j] = sc;
  shift0[j] = b0[j] - mean*sc;
}

__global__ void k_foldW(const float* __restrict__ aW, const float* __restrict__ scale0,
                        float* __restrict__ Wpt, float* __restrict__ Wrelt){
  int idx = blockIdx.x*256 + threadIdx.x;
  if (idx < 20000){
    int d = idx/200, kk = idx%200;
    int k = (kk<100)? kk : kk-100;
    int j = (kk<100)? d : 100+d;
    Wpt[idx] = aW[k*TDIM + j] * scale0[j];
  } else if (idx < 30000){
    int i2 = idx - 20000;
    int d = i2/100, k = i2%100;
    Wrelt[i2] = aW[k*TDIM + 200 + d] * scale0[200+d];
  }
}

__global__ void k_bp(const float* __restrict__ aW, const float* __restrict__ ab,
                     const float* __restrict__ shift0, float* __restrict__ bp){
  int k = blockIdx.x;
  int l = threadIdx.x;            // 64
  float s=0.f;
  for (int j=l;j<TDIM;j+=64) s += aW[k*TDIM+j] * shift0[j];
  #pragma unroll
  for (int m=32;m>=1;m>>=1) s += __shfl_xor(s, m, 64);
  if (l==0) bp[k] = s + ab[k];
}

__global__ void k_V(const float* __restrict__ rel, const float* __restrict__ Wrelt, float* __restrict__ V){
  __shared__ float rf[DIM];
  int r = blockIdx.x;
  int k = threadIdx.x;            // 128
  if (k < DIM) rf[k] = rel[r*DIM+k];
  __syncthreads();
  if (k >= DIM) return;
  float s=0.f;
  for (int d=0;d<DIM;d++) s += Wrelt[d*DIM+k]*rf[d];
  V[r*DIM+k] = s;
}

// ---- UEp[n][256] bf16: U0 at col 0..99, U1 at col 128..227 ----
__global__ __launch_bounds__(256) void k_U(const float* __restrict__ ent, const float* __restrict__ Wpt,
                                           u16* __restrict__ UEp){
  __shared__ float sh[DIM][36];
  int n0 = blockIdx.x*32;         // 3125*32 = 100000
  for (int idx=threadIdx.x; idx<32*DIM; idx+=256){
    int n = idx/DIM, d = idx%DIM;
    sh[d][n] = ent[(size_t)(n0+n)*DIM + d];
  }
  __syncthreads();
  int kk = threadIdx.x;
  if (kk >= 200) return;
  float acc[32];
  #pragma unroll
  for (int i=0;i<32;i++) acc[i]=0.f;
  for (int d=0;d<DIM;d++){
    float w = Wpt[d*200+kk];
    #pragma unroll
    for (int i=0;i<32;i++) acc[i] += w*sh[d][i];
  }
  int col = (kk<100)? kk : (28+kk);   // 128 + (kk-100)
  for (int i=0;i<32;i++) UEp[(size_t)(n0+i)*PITCH + col] = f2bf(acc[i]);
}

// ---- bn1 stats over 2E rows of c_pre (edge sweep, 4 row gathers) ----
__global__ __launch_bounds__(256) void k_cstats(const int* __restrict__ trip,
    const u16* __restrict__ UEp, const float* __restrict__ V, const float* __restrict__ bp,
    float* __restrict__ Sc, float* __restrict__ Sc2){
  __shared__ float scB[DIM], sc2B[DIM];
  for (int i=threadIdx.x;i<DIM;i+=256){ scB[i]=0.f; sc2B[i]=0.f; }
  __syncthreads();
  int lane = threadIdx.x & 31;
  int slot = (blockIdx.x*256 + threadIdx.x) >> 5;
  int nslots = gridDim.x*8;
  bool act = lane < 25;
  int dbase = lane*4;
  float bpv[4]={0,0,0,0};
  if (act) ld4f(bp+dbase, bpv);
  float sc[4]={0,0,0,0}, sc2[4]={0,0,0,0};
  for (int e=slot; e<E_EDGES; e+=nslots){
    int3 t = ((const int3*)trip)[e];
    if (act){
      const u16* rx = UEp + (size_t)t.x*PITCH;
      const u16* ry = UEp + (size_t)t.y*PITCH;
      float P[4],Q[4],R[4],S[4],Vv[4];
      ld4a(rx+dbase, P);          // U0[t0]
      ld4a(ry+128+dbase, Q);      // U1[t1]
      ld4a(ry+dbase, R);          // U0[t1]
      ld4a(rx+128+dbase, S);      // U1[t0]
      ld4f(V+(size_t)t.z*DIM+dbase, Vv);
      #pragma unroll
      for (int i=0;i<4;i++){
        float cf = P[i]+Q[i]+Vv[i]+bpv[i];
        float ci = R[i]+S[i]-Vv[i]+bpv[i];
        sc[i]  += cf+ci;
        sc2[i] += cf*cf + ci*ci;
      }
    }
  }
  if (act){
    #pragma unroll
    for (int i=0;i<4;i++){ atomicAdd(&scB[dbase+i], sc[i]); atomicAdd(&sc2B[dbase+i], sc2[i]); }
  }
  __syncthreads();
  for (int i=threadIdx.x;i<DIM;i+=256){ atomicAdd(&Sc[i], scB[i]); atomicAdd(&Sc2[i], sc2B[i]); }
}

// ---- bn1 affine + attention vector w + scalar C ----
__global__ void k_bn1x(const float* __restrict__ g1, const float* __restrict__ b1,
                       const float* __restrict__ Sc, const float* __restrict__ Sc2,
                       const float* __restrict__ bp, const float* __restrict__ a2W, const float* __restrict__ a2b,
                       float* __restrict__ scale1, float* __restrict__ shift1,
                       float* __restrict__ wvec, float* __restrict__ consts){
  __shared__ float red[128];
  int k = threadIdx.x;            // 128
  float contrib = 0.f;
  if (k < DIM){
    float mean = Sc[k]*(1.0f/TWO_E);
    float var  = Sc2[k]*(1.0f/TWO_E) - mean*mean;
    float s = g1[k] * rsqrtf(var + BN_EPS);
    float sh = b1[k] - mean*s;
    float a2 = a2W[k];
    scale1[k] = s;
    shift1[k] = sh;
    float wv = s*a2;
    wvec[k] = wv;
    contrib = bp[k]*wv + sh*a2;
  }
  red[k] = contrib;
  __syncthreads();
  for (int m=64;m>=1;m>>=1){ if (k<m) red[k]+=red[k+m]; __syncthreads(); }
  if (k==0) consts[0] = red[0] + a2b[0];
}

// ---- phi0[n]=U0[n].w, phi1[n]=U1[n].w ----
__global__ __launch_bounds__(256) void k_phi(const u16* __restrict__ UEp, const float* __restrict__ wvec,
                                             float* __restrict__ phi0, float* __restrict__ phi1){
  int lane = threadIdx.x & 31;
  int n = blockIdx.x*8 + (threadIdx.x>>5);
  bool act = lane < 25;
  int dbase = lane*4;
  float w4[4]={0,0,0,0};
  float p0=0.f, p1=0.f;
  if (act){
    ld4f(wvec+dbase, w4);
    float P[4], Q[4];
    ld4a(UEp + (size_t)n*PITCH + dbase, P);
    ld4a(UEp + (size_t)n*PITCH + 128 + dbase, Q);
    #pragma unroll
    for (int i=0;i<4;i++){ p0 += P[i]*w4[i]; p1 += Q[i]*w4[i]; }
  }
  #pragma unroll
  for (int m=16;m>=1;m>>=1){ p0 += __shfl_xor(p0,m,32); p1 += __shfl_xor(p1,m,32); }
  if (lane==0){ phi0[n]=p0; phi1[n]=p1; }
}

// ---- psi[r]=V[r].w ----
__global__ void k_psi(const float* __restrict__ V, const float* __restrict__ wvec, float* __restrict__ psi){
  __shared__ float w[DIM];
  int t = threadIdx.x;            // 256
  if (t < DIM) w[t] = wvec[t];
  __syncthreads();
  if (t >= NREL) return;
  float s=0.f;
  for (int k=0;k<DIM;k++) s += V[t*DIM+k]*w[k];
  psi[t] = s;
}

// ---- entity aggregation: one 32-lane slot per entity, zero atomics ----
__global__ __launch_bounds__(256) void k_aggr_ent(const u32* __restrict__ offs, const u32* __restrict__ inc,
    const u16* __restrict__ UEp, const float* __restrict__ V,
    const float* __restrict__ phi0, const float* __restrict__ phi1, const float* __restrict__ psi,
    const float* __restrict__ consts, const float* __restrict__ bp,
    const float* __restrict__ scale1, const float* __restrict__ shift1,
    float* __restrict__ out){
  int lane = threadIdx.x & 31;
  int n = blockIdx.x*8 + (threadIdx.x>>5);
  bool act = lane < 25;
  int dbase = lane*4;
  u32 o0 = offs[n], o1 = offs[n+1];
  float C = consts[0];
  float p0n = phi0[n];
  float acc[4]={0,0,0,0};
  float wsum=0.f;
  for (u32 i=o0; i<o1; i++){
    u32 pk = inc[i];
    u32 other = pk & 0x1FFFFu;
    u32 rr = (pk>>17) & 0xFFu;
    bool neg = (pk>>25) != 0u;
    float ps = psi[rr];
    float t = p0n + phi1[other] + (neg ? -ps : ps) + C;
    float w = ewt(t);
    wsum += w;
    if (act){
      float B[4], Vv[4];
      ld4a(UEp + (size_t)other*PITCH + 128 + dbase, B);
      ld4f(V + (size_t)rr*DIM + dbase, Vv);
      float sg = neg ? -1.f : 1.f;
      #pragma unroll
      for (int i2=0;i2<4;i2++) acc[i2] += w*(B[i2]+sg*Vv[i2]);
    }
  }
  if (act){
    float o4[4];
    if (o1 == o0){
      o4[0]=o4[1]=o4[2]=o4[3]=0.f;
    } else {
      float P[4], bp4[4], s14[4], sh4[4];
      ld4a(UEp + (size_t)n*PITCH + dbase, P);
      ld4f(bp+dbase, bp4);
      ld4f(scale1+dbase, s14);
      ld4f(shift1+dbase, sh4);
      float inv = __frcp_rn(wsum);
      #pragma unroll
      for (int i2=0;i2<4;i2++){
        float v = (P[i2]+bp4[i2])*s14[i2] + sh4[i2] + s14[i2]*acc[i2]*inv;
        o4[i2] = eluf(v);
      }
    }
    *(float4*)(out + (size_t)n*DIM + dbase) = make_float4(o4[0],o4[1],o4[2],o4[3]);
  }
}

// ---- rel aggregation: one block per rel, LDS reduce, zero global atomics ----
__global__ __launch_bounds__(256) void k_aggr_rel(const int* __restrict__ trip,
    const u32* __restrict__ roff, const u32* __restrict__ reledge,
    const u16* __restrict__ UEp, const float* __restrict__ V,
    const float* __restrict__ phi0, const float* __restrict__ phi1, const float* __restrict__ psi,
    const float* __restrict__ consts, const float* __restrict__ bp,
    const float* __restrict__ scale1, const float* __restrict__ shift1,
    const float* __restrict__ relcnt, float* __restrict__ out){
  __shared__ float red[8][104];
  int r = blockIdx.x;
  int lane = threadIdx.x & 31;
  int slot = threadIdx.x >> 5;    // 8 slots
  bool act = lane < 25;
  int dbase = lane*4;
  float C = consts[0];
  float psir = psi[r];
  float bp4[4]={0,0,0,0}, s14[4]={0,0,0,0}, sh4[4]={0,0,0,0}, Vv[4]={0,0,0,0};
  if (act){
    ld4f(bp+dbase, bp4);
    ld4f(scale1+dbase, s14);
    ld4f(shift1+dbase, sh4);
    ld4f(V + (size_t)r*DIM + dbase, Vv);
  }
  u32 q0 = roff[r], q1 = roff[r+1];
  float acc[4]={0,0,0,0};
  for (u32 q=q0+slot; q<q1; q+=8){
    int e = (int)reledge[q];
    int3 t = ((const int3*)trip)[e];
    float tf = phi0[t.x] + phi1[t.y] + psir + C;
    float ti = phi0[t.y] + phi1[t.x] - psir + C;
    float ef = ewt(tf);
    float ei = ewt(ti);
    if (act){
      const u16* rx = UEp + (size_t)t.x*PITCH;
      const u16* ry = UEp + (size_t)t.y*PITCH;
      float P[4],Q[4],R[4],S[4];
      ld4a(rx+dbase, P);
      ld4a(ry+128+dbase, Q);
      ld4a(ry+dbase, R);
      ld4a(rx+128+dbase, S);
      #pragma unroll
      for (int i=0;i<4;i++){
        float cf = (P[i]+Q[i]+Vv[i]+bp4[i])*s14[i] + sh4[i];
        float ci = (R[i]+S[i]-Vv[i]+bp4[i])*s14[i] + sh4[i];
        acc[i] += ef*cf - ei*ci;
      }
    }
  }
  if (act){
    #pragma unroll
    for (int i=0;i<4;i++) red[slot][dbase+i] = acc[i];
  }
  __syncthreads();
  int k = threadIdx.x;
  if (k < DIM){
    float s = 0.f;
    #pragma unroll
    for (int sl=0;sl<8;sl++) s += red[sl][k];
    float cn = relcnt[r]; if (cn < 1.f) cn = 1.f;
    out[(size_t)NENT*DIM + (size_t)r*DIM + k] = eluf(s/cn);
  }
}

extern "C" void kernel_launch(void* const* d_in, const int* in_sizes, int n_in,
                              void* d_out, int out_size, void* d_ws, size_t ws_size,
                              hipStream_t stream){
  const int*   trip = (const int*)d_in[0];
  const float* ent  = (const float*)d_in[1];
  const float* rel  = (const float*)d_in[2];
  const float* aW   = (const float*)d_in[3];
  const float* ab   = (const float*)d_in[4];
  const float* a2W  = (const float*)d_in[5];
  const float* a2b  = (const float*)d_in[6];
  const float* g0   = (const float*)d_in[7];
  const float* b0   = (const float*)d_in[8];
  const float* g1   = (const float*)d_in[9];
  const float* b1   = (const float*)d_in[10];
  float* out = (float*)d_out;
  float* wsf = (float*)d_ws;
  if (ws_size < TOTAL_F*sizeof(float)) return;
  u16* UEp  = (u16*)(wsf + OFF_UE);
  u32* deg  = (u32*)(wsf + OFF_DEG);
  u32* cur  = (u32*)(wsf + OFF_CUR);
  u32* offs = (u32*)(wsf + OFF_OFFS);
  u32* roff = (u32*)(wsf + OFF_ROFF);
  u32* bhist= (u32*)(wsf + OFF_BHIST);
  u32* rbase= (u32*)(wsf + OFF_RBASE);
  u32* inc  = (u32*)(wsf + OFF_INC);
  u32* rele = (u32*)(wsf + OFF_RELEDGE);

  hipMemsetAsync(d_ws, 0, ZERO_END*sizeof(float), stream);

  k_histA<<<dim3(NB), dim3(256), 0, stream>>>(trip, deg, bhist);
  k_entstats<<<dim3((NENT+255)/256), dim3(128), 0, stream>>>(ent, deg, wsf+OFF_S1, wsf+OFF_S2);
  k_scan<<<dim3(1), dim3(256), 0, stream>>>(deg, bhist, offs, roff, rbase, wsf+OFF_RELCNTF);
  k_relstats<<<dim3(1), dim3(128), 0, stream>>>(rel, wsf+OFF_RELCNTF, wsf+OFF_S2R);
  k_scale0<<<dim3(1), dim3(320), 0, stream>>>(g0, b0, wsf+OFF_S1, wsf+OFF_S2, wsf+OFF_S2R,
                                              wsf+OFF_SCALE0, wsf+OFF_SHIFT0);
  k_foldW<<<dim3(118), dim3(256), 0, stream>>>(aW, wsf+OFF_SCALE0, wsf+OFF_WPT, wsf+OFF_WRELT);
  k_bp<<<dim3(100), dim3(64), 0, stream>>>(aW, ab, wsf+OFF_SHIFT0, wsf+OFF_BP);
  k_V<<<dim3(NREL), dim3(128), 0, stream>>>(rel, wsf+OFF_WRELT, wsf+OFF_V);
  k_U<<<dim3(NENT/32), dim3(256), 0, stream>>>(ent, wsf+OFF_WPT, UEp);
  k_incB<<<dim3(NB), dim3(256), 0, stream>>>(trip, offs, cur, roff, rbase, inc, rele);
  k_cstats<<<dim3(2048), dim3(256), 0, stream>>>(trip, UEp, wsf+OFF_V, wsf+OFF_BP,
                                                 wsf+OFF_SC, wsf+OFF_SC2);
  k_bn1x<<<dim3(1), dim3(128), 0, stream>>>(g1, b1, wsf+OFF_SC, wsf+OFF_SC2, wsf+OFF_BP, a2W, a2b,
                                            wsf+OFF_SCALE1, wsf+OFF_SHIFT1, wsf+OFF_WVEC, wsf+OFF_CONST);
  k_phi<<<dim3(NENT/8), dim3(256), 0, stream>>>(UEp, wsf+OFF_WVEC, wsf+OFF_PHI0, wsf+OFF_PHI1);
  k_psi<<<dim3(1), dim3(256), 0, stream>>>(wsf+OFF_V, wsf+OFF_WVEC, wsf+OFF_PSI);
  k_aggr_ent<<<dim3(NENT/8), dim3(256), 0, stream>>>(offs, inc, UEp, wsf+OFF_V,
                                                     wsf+OFF_PHI0, wsf+OFF_PHI1, wsf+OFF_PSI,
                                                     wsf+OFF_CONST, wsf+OFF_BP,
                                                     wsf+OFF_SCALE1, wsf+OFF_SHIFT1, out);
  k_aggr_rel<<<dim3(NREL), dim3(256), 0, stream>>>(trip, roff, rele, UEp, wsf+OFF_V,
                                                   wsf+OFF_PHI0, wsf+OFF_PHI1, wsf+OFF_PSI,
                                                   wsf+OFF_CONST, wsf+OFF_BP,
                                                   wsf+OFF_SCALE1, wsf+OFF_SHIFT1,
                                                   wsf+OFF_RELCNTF, out);
}

// Round 5
// 860.245 us; speedup vs baseline: 3.3719x; 1.1960x over previous
//
#include <hip/hip_runtime.h>
#include <hip/hip_bf16.h>

#define E_EDGES 500000
#define NENT    100000
#define NREL    237
#define DIM     100
#define TDIM    300
#define TWO_E   1000000
#define BN_EPS  1e-5f
#define PITCH   256        // u16 elems per UEp row (512B): U0 at +0, U1 at +128
#define NB      512        // histogram/scatter blocks
#define CHUNK   977        // ceil(E_EDGES/NB)
#define RSEG    16         // segments per rel in rel-aggregation

typedef unsigned short u16;
typedef unsigned int   u32;
typedef unsigned long long u64;

// ---------- ws layout (offsets in floats) ----------
static const size_t OFF_DEG     = 0;         // u32[100000] (zeroed)
static const size_t OFF_CUR     = 100000;    // u32[100000] (zeroed)
static const size_t OFF_S1      = 200000;    // 128 (zeroed)
static const size_t OFF_S2      = 200128;    // 128 (zeroed)
static const size_t OFF_S2R     = 200256;    // 128 (zeroed)
static const size_t OFF_SC      = 200384;    // 128 (zeroed)
static const size_t OFF_SC2     = 200512;    // 128 (zeroed)
static const size_t OFF_CONST   = 200640;    // 64  (zeroed)
static const size_t OFF_RELACC  = 200704;    // 23744 (zeroed)
static const size_t ZERO_END    = 224448;
static const size_t OFF_OFFS    = 224448;    // u32[100001]
static const size_t OFF_ROFF    = 324464;    // u32[240]
static const size_t OFF_RELCNTF = 324704;    // float[256]
static const size_t OFF_BHIST   = 324960;    // u32[NB*256]
static const size_t OFF_RBASE   = 456032;    // u32[237*NB]
static const size_t OFF_SCALE0  = 577376;    // 320
static const size_t OFF_SHIFT0  = 577696;    // 320
static const size_t OFF_BP      = 578016;    // 128
static const size_t OFF_SCALE1  = 578144;    // 128
static const size_t OFF_SHIFT1  = 578272;    // 128
static const size_t OFF_WVEC    = 578400;    // 128
static const size_t OFF_WPT     = 578528;    // 100*200
static const size_t OFF_WRELT   = 598528;    // 100*100
static const size_t OFF_V       = 608528;    // 237*100 (pitch 100 f32)
static const size_t OFF_PSI     = 632272;    // 256
static const size_t OFF_PHI0    = 632528;    // 100000
static const size_t OFF_PHI1    = 732528;    // 100000
static const size_t OFF_RELE64  = 832528;    // u64[500000] = 1000000 floats (8B aligned: even)
static const size_t OFF_INC     = 1832528;   // u32[1000000]
static const size_t OFF_UE      = 2832528;   // u16[100000*256] = 12.8M floats
static const size_t TOTAL_F     = 15632528;  // ~62.5 MB

__device__ __forceinline__ float bf2f(u16 u){ return __uint_as_float(((u32)u)<<16); }
__device__ __forceinline__ u16 f2bf(float f){
  u32 x = __float_as_uint(f);
  x += 0x7FFFu + ((x>>16)&1u);
  return (u16)(x>>16);
}
__device__ __forceinline__ void ld4a(const u16* p, float* o){
  ushort4 u = *(const ushort4*)p;
  o[0]=bf2f(u.x); o[1]=bf2f(u.y); o[2]=bf2f(u.z); o[3]=bf2f(u.w);
}
__device__ __forceinline__ void ld4f(const float* p, float* o){
  float4 v = *(const float4*)p;
  o[0]=v.x; o[1]=v.y; o[2]=v.z; o[3]=v.w;
}
__device__ __forceinline__ float eluf(float v){ return v>0.f ? v : expf(v)-1.f; }
__device__ __forceinline__ float ewt(float t){ return expf( t>0.f ? -t : -0.01f*t ); }

// ---- pass A: deg atomics (spread) + per-block rel histogram in LDS ----
__global__ __launch_bounds__(256) void k_histA(const int* __restrict__ trip,
                                               u32* __restrict__ deg, u32* __restrict__ bhist){
  __shared__ u32 lh[256];
  int t = threadIdx.x, b = blockIdx.x;
  lh[t] = 0u;
  __syncthreads();
  int e0 = b*CHUNK, e1 = e0+CHUNK; if (e1 > E_EDGES) e1 = E_EDGES;
  for (int e=e0+t; e<e1; e+=256){
    int3 tr = ((const int3*)trip)[e];
    atomicAdd(&deg[tr.x], 1u);
    atomicAdd(&deg[tr.y], 1u);
    atomicAdd(&lh[tr.z], 1u);
  }
  __syncthreads();
  bhist[b*256 + t] = lh[t];
}

// ---- scan: entity CSR offsets + rel per-block bases (deterministic) ----
__global__ void k_scan(const u32* __restrict__ deg, const u32* __restrict__ bhist,
                       u32* __restrict__ offs, u32* __restrict__ roff,
                       u32* __restrict__ rbase, float* __restrict__ relcntf){
  __shared__ u32 part[256];
  __shared__ u32 base[256];
  __shared__ u32 rtot[256];
  int t = threadIdx.x;
  int c0 = t*391, c1 = c0+391; if (c1 > NENT) c1 = NENT; if (c0 > NENT) c0 = NENT;
  u32 s=0;
  for (int n=c0;n<c1;n++) s += deg[n];
  part[t]=s; __syncthreads();
  if (t==0){ u32 run=0; for (int i=0;i<256;i++){ base[i]=run; run+=part[i]; } }
  __syncthreads();
  u32 run = base[t];
  for (int n=c0;n<c1;n++){ offs[n]=run; run += deg[n]; }
  if (t==255) offs[NENT] = run;
  u32 rr=0;
  if (t < NREL){
    for (int b=0;b<NB;b++){ rbase[t*NB+b]=rr; rr += bhist[b*256+t]; }
  }
  rtot[t]=rr;
  __syncthreads();
  if (t==0){
    u32 r=0;
    for (int i=0;i<NREL;i++){ roff[i]=r; relcntf[i]=(float)rtot[i]; r+=rtot[i]; }
    roff[NREL]=r;
  }
}

// ---- pass B: fill incidence lists (rel part atomic-free, packed endpoints) ----
__global__ __launch_bounds__(256) void k_incB(const int* __restrict__ trip,
                      const u32* __restrict__ offs, u32* __restrict__ cur,
                      const u32* __restrict__ roff, const u32* __restrict__ rbase,
                      u32* __restrict__ inc, u64* __restrict__ rele64){
  __shared__ u32 lh[256];
  int t = threadIdx.x, b = blockIdx.x;
  lh[t] = 0u;
  __syncthreads();
  int e0 = b*CHUNK, e1 = e0+CHUNK; if (e1 > E_EDGES) e1 = E_EDGES;
  for (int e=e0+t; e<e1; e+=256){
    int3 tr = ((const int3*)trip)[e];
    u32 p0 = offs[tr.x] + atomicAdd(&cur[tr.x], 1u);
    inc[p0] = (u32)tr.y | ((u32)tr.z<<17);
    u32 p1 = offs[tr.y] + atomicAdd(&cur[tr.y], 1u);
    inc[p1] = (u32)tr.x | ((u32)tr.z<<17) | (1u<<25);
    u32 loff = atomicAdd(&lh[tr.z], 1u);
    rele64[roff[tr.z] + rbase[(u32)tr.z*NB + b] + loff] = (u64)(u32)tr.x | ((u64)(u32)tr.y<<17);
  }
}

// ---- bn0 entity-column stats (degree-weighted) ----
__global__ void k_entstats(const float* __restrict__ ent, const u32* __restrict__ deg,
                           float* __restrict__ S1, float* __restrict__ S2){
  int d = threadIdx.x;            // 128, d<100 active
  if (d >= DIM) return;
  int n0 = blockIdx.x*256;
  int nend = n0+256; if (nend > NENT) nend = NENT;
  float s1=0.f, s2=0.f;
  for (int n=n0;n<nend;n++){
    float w = (float)deg[n];
    float x = ent[(size_t)n*DIM + d];
    s1 += w*x; s2 += w*x*x;
  }
  atomicAdd(&S1[d], s1);
  atomicAdd(&S2[d], s2);
}

__global__ void k_relstats(const float* __restrict__ rel, const float* __restrict__ relcnt, float* __restrict__ S2r){
  int d = threadIdx.x;
  if (d >= DIM) return;
  float s=0.f;
  for (int r=0;r<NREL;r++){
    float x = rel[r*DIM+d];
    s += relcnt[r]*x*x;
  }
  S2r[d] = s;
}

__global__ void k_scale0(const float* __restrict__ g0, const float* __restrict__ b0,
                         const float* __restrict__ S1, const float* __restrict__ S2, const float* __restrict__ S2r,
                         float* __restrict__ scale0, float* __restrict__ shift0){
  int j = threadIdx.x;            // 320
  if (j >= TDIM) return;
  float mean, var;
  if (j < 200){
    int d = (j<100)? j : j-100;
    mean = S1[d] * (1.0f/TWO_E);
    var  = S2[d] * (1.0f/TWO_E) - mean*mean;
  } else {
    mean = 0.0f;
    var  = S2r[j-200] * (1.0f/E_EDGES);
  }
  float sc = g0[j] * rsqrtf(var + BN_EPS);
  scale0[j] = sc;
  shift0[j] = b0[j] - mean*sc;
}

__global__ void k_foldW(const float* __restrict__ aW, const float* __restrict__ scale0,
                        float* __restrict__ Wpt, float* __restrict__ Wrelt){
  int idx = blockIdx.x*256 + threadIdx.x;
  if (idx < 20000){
    int d = idx/200, kk = idx%200;
    int k = (kk<100)? kk : kk-100;
    int j = (kk<100)? d : 100+d;
    Wpt[idx] = aW[k*TDIM + j] * scale0[j];
  } else if (idx < 30000){
    int i2 = idx - 20000;
    int d = i2/100, k = i2%100;
    Wrelt[i2] = aW[k*TDIM + 200 + d] * scale0[200+d];
  }
}

__global__ void k_bp(const float* __restrict__ aW, const float* __restrict__ ab,
                     const float* __restrict__ shift0, float* __restrict__ bp){
  int k = blockIdx.x;
  int l = threadIdx.x;            // 64
  float s=0.f;
  for (int j=l;j<TDIM;j+=64) s += aW[k*TDIM+j] * shift0[j];
  #pragma unroll
  for (int m=32;m>=1;m>>=1) s += __shfl_xor(s, m, 64);
  if (l==0) bp[k] = s + ab[k];
}

__global__ void k_V(const float* __restrict__ rel, const float* __restrict__ Wrelt, float* __restrict__ V){
  __shared__ float rf[DIM];
  int r = blockIdx.x;
  int k = threadIdx.x;            // 128
  if (k < DIM) rf[k] = rel[r*DIM+k];
  __syncthreads();
  if (k >= DIM) return;
  float s=0.f;
  for (int d=0;d<DIM;d++) s += Wrelt[d*DIM+k]*rf[d];
  V[r*DIM+k] = s;
}

// ---- UEp[n][256] bf16: U0 at col 0..99, U1 at col 128..227 ----
__global__ __launch_bounds__(256) void k_U(const float* __restrict__ ent, const float* __restrict__ Wpt,
                                           u16* __restrict__ UEp){
  __shared__ float sh[DIM][36];
  int n0 = blockIdx.x*32;         // 3125*32 = 100000
  for (int idx=threadIdx.x; idx<32*DIM; idx+=256){
    int n = idx/DIM, d = idx%DIM;
    sh[d][n] = ent[(size_t)(n0+n)*DIM + d];
  }
  __syncthreads();
  int kk = threadIdx.x;
  if (kk >= 200) return;
  float acc[32];
  #pragma unroll
  for (int i=0;i<32;i++) acc[i]=0.f;
  for (int d=0;d<DIM;d++){
    float w = Wpt[d*200+kk];
    #pragma unroll
    for (int i=0;i<32;i++) acc[i] += w*sh[d][i];
  }
  int col = (kk<100)? kk : (28+kk);   // 128 + (kk-100)
  for (int i=0;i<32;i++) UEp[(size_t)(n0+i)*PITCH + col] = f2bf(acc[i]);
}

// ---- bn1 stats over 2E rows of c_pre (edge sweep, 4 row gathers) ----
__global__ __launch_bounds__(256) void k_cstats(const int* __restrict__ trip,
    const u16* __restrict__ UEp, const float* __restrict__ V, const float* __restrict__ bp,
    float* __restrict__ Sc, float* __restrict__ Sc2){
  __shared__ float scB[DIM], sc2B[DIM];
  for (int i=threadIdx.x;i<DIM;i+=256){ scB[i]=0.f; sc2B[i]=0.f; }
  __syncthreads();
  int lane = threadIdx.x & 31;
  int slot = (blockIdx.x*256 + threadIdx.x) >> 5;
  int nslots = gridDim.x*8;
  bool act = lane < 25;
  int dbase = lane*4;
  float bpv[4]={0,0,0,0};
  if (act) ld4f(bp+dbase, bpv);
  float sc[4]={0,0,0,0}, sc2[4]={0,0,0,0};
  for (int e=slot; e<E_EDGES; e+=nslots){
    int3 t = ((const int3*)trip)[e];
    if (act){
      const u16* rx = UEp + (size_t)t.x*PITCH;
      const u16* ry = UEp + (size_t)t.y*PITCH;
      float P[4],Q[4],R[4],S[4],Vv[4];
      ld4a(rx+dbase, P);          // U0[t0]
      ld4a(ry+128+dbase, Q);      // U1[t1]
      ld4a(ry+dbase, R);          // U0[t1]
      ld4a(rx+128+dbase, S);      // U1[t0]
      ld4f(V+(size_t)t.z*DIM+dbase, Vv);
      #pragma unroll
      for (int i=0;i<4;i++){
        float cf = P[i]+Q[i]+Vv[i]+bpv[i];
        float ci = R[i]+S[i]-Vv[i]+bpv[i];
        sc[i]  += cf+ci;
        sc2[i] += cf*cf + ci*ci;
      }
    }
  }
  if (act){
    #pragma unroll
    for (int i=0;i<4;i++){ atomicAdd(&scB[dbase+i], sc[i]); atomicAdd(&sc2B[dbase+i], sc2[i]); }
  }
  __syncthreads();
  for (int i=threadIdx.x;i<DIM;i+=256){ atomicAdd(&Sc[i], scB[i]); atomicAdd(&Sc2[i], sc2B[i]); }
}

// ---- bn1 affine + attention vector w + scalar C ----
__global__ void k_bn1x(const float* __restrict__ g1, const float* __restrict__ b1,
                       const float* __restrict__ Sc, const float* __restrict__ Sc2,
                       const float* __restrict__ bp, const float* __restrict__ a2W, const float* __restrict__ a2b,
                       float* __restrict__ scale1, float* __restrict__ shift1,
                       float* __restrict__ wvec, float* __restrict__ consts){
  __shared__ float red[128];
  int k = threadIdx.x;            // 128
  float contrib = 0.f;
  if (k < DIM){
    float mean = Sc[k]*(1.0f/TWO_E);
    float var  = Sc2[k]*(1.0f/TWO_E) - mean*mean;
    float s = g1[k] * rsqrtf(var + BN_EPS);
    float sh = b1[k] - mean*s;
    float a2 = a2W[k];
    scale1[k] = s;
    shift1[k] = sh;
    float wv = s*a2;
    wvec[k] = wv;
    contrib = bp[k]*wv + sh*a2;
  }
  red[k] = contrib;
  __syncthreads();
  for (int m=64;m>=1;m>>=1){ if (k<m) red[k]+=red[k+m]; __syncthreads(); }
  if (k==0) consts[0] = red[0] + a2b[0];
}

// ---- phi0[n]=U0[n].w, phi1[n]=U1[n].w ----
__global__ __launch_bounds__(256) void k_phi(const u16* __restrict__ UEp, const float* __restrict__ wvec,
                                             float* __restrict__ phi0, float* __restrict__ phi1){
  int lane = threadIdx.x & 31;
  int n = blockIdx.x*8 + (threadIdx.x>>5);
  bool act = lane < 25;
  int dbase = lane*4;
  float w4[4]={0,0,0,0};
  float p0=0.f, p1=0.f;
  if (act){
    ld4f(wvec+dbase, w4);
    float P[4], Q[4];
    ld4a(UEp + (size_t)n*PITCH + dbase, P);
    ld4a(UEp + (size_t)n*PITCH + 128 + dbase, Q);
    #pragma unroll
    for (int i=0;i<4;i++){ p0 += P[i]*w4[i]; p1 += Q[i]*w4[i]; }
  }
  #pragma unroll
  for (int m=16;m>=1;m>>=1){ p0 += __shfl_xor(p0,m,32); p1 += __shfl_xor(p1,m,32); }
  if (lane==0){ phi0[n]=p0; phi1[n]=p1; }
}

// ---- psi[r]=V[r].w ----
__global__ void k_psi(const float* __restrict__ V, const float* __restrict__ wvec, float* __restrict__ psi){
  __shared__ float w[DIM];
  int t = threadIdx.x;            // 256
  if (t < DIM) w[t] = wvec[t];
  __syncthreads();
  if (t >= NREL) return;
  float s=0.f;
  for (int k=0;k<DIM;k++) s += V[t*DIM+k]*w[k];
  psi[t] = s;
}

// ---- entity aggregation: one 32-lane slot per entity, zero atomics ----
__global__ __launch_bounds__(256) void k_aggr_ent(const u32* __restrict__ offs, const u32* __restrict__ inc,
    const u16* __restrict__ UEp, const float* __restrict__ V,
    const float* __restrict__ phi0, const float* __restrict__ phi1, const float* __restrict__ psi,
    const float* __restrict__ consts, const float* __restrict__ bp,
    const float* __restrict__ scale1, const float* __restrict__ shift1,
    float* __restrict__ out){
  int lane = threadIdx.x & 31;
  int n = blockIdx.x*8 + (threadIdx.x>>5);
  bool act = lane < 25;
  int dbase = lane*4;
  u32 o0 = offs[n], o1 = offs[n+1];
  float C = consts[0];
  float p0n = phi0[n];
  float acc[4]={0,0,0,0};
  float wsum=0.f;
  for (u32 i=o0; i<o1; i++){
    u32 pk = inc[i];
    u32 other = pk & 0x1FFFFu;
    u32 rr = (pk>>17) & 0xFFu;
    bool neg = (pk>>25) != 0u;
    float ps = psi[rr];
    float t = p0n + phi1[other] + (neg ? -ps : ps) + C;
    float w = ewt(t);
    wsum += w;
    if (act){
      float B[4], Vv[4];
      ld4a(UEp + (size_t)other*PITCH + 128 + dbase, B);
      ld4f(V + (size_t)rr*DIM + dbase, Vv);
      float sg = neg ? -1.f : 1.f;
      #pragma unroll
      for (int i2=0;i2<4;i2++) acc[i2] += w*(B[i2]+sg*Vv[i2]);
    }
  }
  if (act){
    float o4[4];
    if (o1 == o0){
      o4[0]=o4[1]=o4[2]=o4[3]=0.f;
    } else {
      float P[4], bp4[4], s14[4], sh4[4];
      ld4a(UEp + (size_t)n*PITCH + dbase, P);
      ld4f(bp+dbase, bp4);
      ld4f(scale1+dbase, s14);
      ld4f(shift1+dbase, sh4);
      float inv = __frcp_rn(wsum);
      #pragma unroll
      for (int i2=0;i2<4;i2++){
        float v = (P[i2]+bp4[i2])*s14[i2] + sh4[i2] + s14[i2]*acc[i2]*inv;
        o4[i2] = eluf(v);
      }
    }
    *(float4*)(out + (size_t)n*DIM + dbase) = make_float4(o4[0],o4[1],o4[2],o4[3]);
  }
}

// ---- rel aggregation: NREL*RSEG blocks, LDS reduce + one atomic burst/block ----
__global__ __launch_bounds__(256) void k_aggr_relP(
    const u32* __restrict__ roff, const u64* __restrict__ rele64,
    const u16* __restrict__ UEp, const float* __restrict__ V,
    const float* __restrict__ phi0, const float* __restrict__ phi1, const float* __restrict__ psi,
    const float* __restrict__ consts, const float* __restrict__ bp,
    const float* __restrict__ scale1, const float* __restrict__ shift1,
    float* __restrict__ relacc){
  __shared__ float red[8][104];
  int r   = blockIdx.x / RSEG;
  int seg = blockIdx.x % RSEG;
  int lane = threadIdx.x & 31;
  int slot = threadIdx.x >> 5;    // 8 slots
  bool act = lane < 25;
  int dbase = lane*4;
  float C = consts[0];
  float psir = psi[r];
  float bp4[4]={0,0,0,0}, s14[4]={0,0,0,0}, sh4[4]={0,0,0,0}, Vv[4]={0,0,0,0};
  if (act){
    ld4f(bp+dbase, bp4);
    ld4f(scale1+dbase, s14);
    ld4f(shift1+dbase, sh4);
    ld4f(V + (size_t)r*DIM + dbase, Vv);
  }
  u32 q0 = roff[r], q1 = roff[r+1];
  float acc[4]={0,0,0,0};
  for (u32 q = q0 + (u32)(seg*8+slot); q < q1; q += RSEG*8){
    u64 pk = rele64[q];
    u32 t0 = (u32)(pk & 0x1FFFFu);
    u32 t1 = (u32)((pk>>17) & 0x1FFFFu);
    float tf = phi0[t0] + phi1[t1] + psir + C;
    float ti = phi0[t1] + phi1[t0] - psir + C;
    float ef = ewt(tf);
    float ei = ewt(ti);
    if (act){
      const u16* rx = UEp + (size_t)t0*PITCH;
      const u16* ry = UEp + (size_t)t1*PITCH;
      float P[4],Q[4],R[4],S[4];
      ld4a(rx+dbase, P);
      ld4a(ry+128+dbase, Q);
      ld4a(ry+dbase, R);
      ld4a(rx+128+dbase, S);
      #pragma unroll
      for (int i=0;i<4;i++){
        float cf = (P[i]+Q[i]+Vv[i]+bp4[i])*s14[i] + sh4[i];
        float ci = (R[i]+S[i]-Vv[i]+bp4[i])*s14[i] + sh4[i];
        acc[i] += ef*cf - ei*ci;
      }
    }
  }
  if (act){
    #pragma unroll
    for (int i=0;i<4;i++) red[slot][dbase+i] = acc[i];
  }
  __syncthreads();
  int k = threadIdx.x;
  if (k < DIM){
    float s = 0.f;
    #pragma unroll
    for (int sl=0;sl<8;sl++) s += red[sl][k];
    atomicAdd(&relacc[(size_t)r*DIM + k], s);
  }
}

// ---- finalize h_rel ----
__global__ void k_out_rel(const float* __restrict__ relacc, const float* __restrict__ relcnt,
                          float* __restrict__ out){
  int idx = blockIdx.x*256 + threadIdx.x;
  if (idx >= NREL*DIM) return;
  int r = idx/DIM;
  float cn = relcnt[r]; if (cn < 1.f) cn = 1.f;
  out[(size_t)NENT*DIM + idx] = eluf(relacc[idx]/cn);
}

extern "C" void kernel_launch(void* const* d_in, const int* in_sizes, int n_in,
                              void* d_out, int out_size, void* d_ws, size_t ws_size,
                              hipStream_t stream){
  const int*   trip = (const int*)d_in[0];
  const float* ent  = (const float*)d_in[1];
  const float* rel  = (const float*)d_in[2];
  const float* aW   = (const float*)d_in[3];
  const float* ab   = (const float*)d_in[4];
  const float* a2W  = (const float*)d_in[5];
  const float* a2b  = (const float*)d_in[6];
  const float* g0   = (const float*)d_in[7];
  const float* b0   = (const float*)d_in[8];
  const float* g1   = (const float*)d_in[9];
  const float* b1   = (const float*)d_in[10];
  float* out = (float*)d_out;
  float* wsf = (float*)d_ws;
  if (ws_size < TOTAL_F*sizeof(float)) return;
  u16* UEp  = (u16*)(wsf + OFF_UE);
  u32* deg  = (u32*)(wsf + OFF_DEG);
  u32* cur  = (u32*)(wsf + OFF_CUR);
  u32* offs = (u32*)(wsf + OFF_OFFS);
  u32* roff = (u32*)(wsf + OFF_ROFF);
  u32* bhist= (u32*)(wsf + OFF_BHIST);
  u32* rbase= (u32*)(wsf + OFF_RBASE);
  u32* inc  = (u32*)(wsf + OFF_INC);
  u64* rele = (u64*)(wsf + OFF_RELE64);

  hipMemsetAsync(d_ws, 0, ZERO_END*sizeof(float), stream);

  k_histA<<<dim3(NB), dim3(256), 0, stream>>>(trip, deg, bhist);
  k_entstats<<<dim3((NENT+255)/256), dim3(128), 0, stream>>>(ent, deg, wsf+OFF_S1, wsf+OFF_S2);
  k_scan<<<dim3(1), dim3(256), 0, stream>>>(deg, bhist, offs, roff, rbase, wsf+OFF_RELCNTF);
  k_relstats<<<dim3(1), dim3(128), 0, stream>>>(rel, wsf+OFF_RELCNTF, wsf+OFF_S2R);
  k_scale0<<<dim3(1), dim3(320), 0, stream>>>(g0, b0, wsf+OFF_S1, wsf+OFF_S2, wsf+OFF_S2R,
                                              wsf+OFF_SCALE0, wsf+OFF_SHIFT0);
  k_foldW<<<dim3(118), dim3(256), 0, stream>>>(aW, wsf+OFF_SCALE0, wsf+OFF_WPT, wsf+OFF_WRELT);
  k_bp<<<dim3(100), dim3(64), 0, stream>>>(aW, ab, wsf+OFF_SHIFT0, wsf+OFF_BP);
  k_V<<<dim3(NREL), dim3(128), 0, stream>>>(rel, wsf+OFF_WRELT, wsf+OFF_V);
  k_U<<<dim3(NENT/32), dim3(256), 0, stream>>>(ent, wsf+OFF_WPT, UEp);
  k_incB<<<dim3(NB), dim3(256), 0, stream>>>(trip, offs, cur, roff, rbase, inc, rele);
  k_cstats<<<dim3(2048), dim3(256), 0, stream>>>(trip, UEp, wsf+OFF_V, wsf+OFF_BP,
                                                 wsf+OFF_SC, wsf+OFF_SC2);
  k_bn1x<<<dim3(1), dim3(128), 0, stream>>>(g1, b1, wsf+OFF_SC, wsf+OFF_SC2, wsf+OFF_BP, a2W, a2b,
                                            wsf+OFF_SCALE1, wsf+OFF_SHIFT1, wsf+OFF_WVEC, wsf+OFF_CONST);
  k_phi<<<dim3(NENT/8), dim3(256), 0, stream>>>(UEp, wsf+OFF_WVEC, wsf+OFF_PHI0, wsf+OFF_PHI1);
  k_psi<<<dim3(1), dim3(256), 0, stream>>>(wsf+OFF_V, wsf+OFF_WVEC, wsf+OFF_PSI);
  k_aggr_ent<<<dim3(NENT/8), dim3(256), 0, stream>>>(offs, inc, UEp, wsf+OFF_V,
                                                     wsf+OFF_PHI0, wsf+OFF_PHI1, wsf+OFF_PSI,
                                                     wsf+OFF_CONST, wsf+OFF_BP,
                                                     wsf+OFF_SCALE1, wsf+OFF_SHIFT1, out);
  k_aggr_relP<<<dim3(NREL*RSEG), dim3(256), 0, stream>>>(roff, rele, UEp, wsf+OFF_V,
                                                   wsf+OFF_PHI0, wsf+OFF_PHI1, wsf+OFF_PSI,
                                                   wsf+OFF_CONST, wsf+OFF_BP,
                                                   wsf+OFF_SCALE1, wsf+OFF_SHIFT1,
                                                   wsf+OFF_RELACC);
  k_out_rel<<<dim3((NREL*DIM+255)/256), dim3(256), 0, stream>>>(wsf+OFF_RELACC, wsf+OFF_RELCNTF, out);
}

// Round 6
// 668.105 us; speedup vs baseline: 4.3416x; 1.2876x over previous
//
#include <hip/hip_runtime.h>
#include <hip/hip_bf16.h>

#define E_EDGES 500000
#define NENT    100000
#define NREL    237
#define DIM     100
#define TDIM    300
#define TWO_E   1000000
#define BN_EPS  1e-5f
#define PITCH   256        // u16 elems per UEp row (512B): U0 at +0, U1 at +128
#define NB      512        // histogram/scatter blocks
#define CHUNK   977        // ceil(E_EDGES/NB)
#define RSEG    16         // segments per rel in rel-aggregation
#define ECHUNK  391        // entities per scan chunk (256*391 >= NENT)

typedef unsigned short u16;
typedef unsigned int   u32;
typedef unsigned long long u64;

// ---------- ws layout (offsets in floats) ----------
static const size_t OFF_DEG     = 0;         // u32[100000] (zeroed)
static const size_t OFF_CUR     = 100000;    // u32[100000] (zeroed)
static const size_t OFF_S1      = 200000;    // 128 (zeroed)
static const size_t OFF_S2      = 200128;    // 128 (zeroed)
static const size_t OFF_S2R     = 200256;    // 128 (zeroed)
static const size_t OFF_SC      = 200384;    // 128 (zeroed)
static const size_t OFF_SC2     = 200512;    // 128 (zeroed)
static const size_t OFF_CONST   = 200640;    // 64  (zeroed)
static const size_t OFF_RELACC  = 200704;    // 23744 (zeroed)
static const size_t ZERO_END    = 224448;
static const size_t OFF_OFFS    = 224448;    // u32[100001]
static const size_t OFF_ROFF    = 324464;    // u32[240]
static const size_t OFF_RELCNTF = 324704;    // float[256]
static const size_t OFF_BHIST   = 324960;    // u32[NB*256]
static const size_t OFF_RBASE   = 456032;    // u32[237*NB]
static const size_t OFF_PART    = 577376;    // u32[256]
static const size_t OFF_BASE    = 577632;    // u32[256]
static const size_t OFF_RTOT    = 577888;    // u32[256]
static const size_t OFF_SCALE0  = 578144;    // 320
static const size_t OFF_SHIFT0  = 578464;    // 320
static const size_t OFF_BP      = 578784;    // 128
static const size_t OFF_SCALE1  = 578912;    // 128
static const size_t OFF_SHIFT1  = 579040;    // 128
static const size_t OFF_WVEC    = 579168;    // 128
static const size_t OFF_WPT     = 579296;    // 100*200
static const size_t OFF_WRELT   = 599296;    // 100*100
static const size_t OFF_V       = 609296;    // 237*100 (pitch 100 f32)
static const size_t OFF_PSI     = 633040;    // 256
static const size_t OFF_PHI0    = 633296;    // 100000
static const size_t OFF_PHI1    = 733296;    // 100000
static const size_t OFF_RELE64  = 833296;    // u64[500000] (even -> 8B aligned)
static const size_t OFF_INC     = 1833296;   // u32[1000000]
static const size_t OFF_UE      = 2833296;   // u16[100000*256] = 12.8M floats
static const size_t TOTAL_F     = 15633296;  // ~62.5 MB

__device__ __forceinline__ float bf2f(u16 u){ return __uint_as_float(((u32)u)<<16); }
__device__ __forceinline__ u16 f2bf(float f){
  u32 x = __float_as_uint(f);
  x += 0x7FFFu + ((x>>16)&1u);
  return (u16)(x>>16);
}
__device__ __forceinline__ void ld4a(const u16* p, float* o){
  ushort4 u = *(const ushort4*)p;
  o[0]=bf2f(u.x); o[1]=bf2f(u.y); o[2]=bf2f(u.z); o[3]=bf2f(u.w);
}
__device__ __forceinline__ void ld4f(const float* p, float* o){
  float4 v = *(const float4*)p;
  o[0]=v.x; o[1]=v.y; o[2]=v.z; o[3]=v.w;
}
__device__ __forceinline__ float eluf(float v){ return v>0.f ? v : expf(v)-1.f; }
__device__ __forceinline__ float ewt(float t){ return expf( t>0.f ? -t : -0.01f*t ); }

// ---- pass A: deg atomics (spread) + per-block rel histogram in LDS ----
__global__ __launch_bounds__(256) void k_histA(const int* __restrict__ trip,
                                               u32* __restrict__ deg, u32* __restrict__ bhist){
  __shared__ u32 lh[256];
  int t = threadIdx.x, b = blockIdx.x;
  lh[t] = 0u;
  __syncthreads();
  int e0 = b*CHUNK, e1 = e0+CHUNK; if (e1 > E_EDGES) e1 = E_EDGES;
  for (int e=e0+t; e<e1; e+=256){
    int3 tr = ((const int3*)trip)[e];
    atomicAdd(&deg[tr.x], 1u);
    atomicAdd(&deg[tr.y], 1u);
    atomicAdd(&lh[tr.z], 1u);
  }
  __syncthreads();
  bhist[b*256 + t] = lh[t];
}

// ---- hierarchical scan, stage A: per-chunk deg sums ----
__global__ __launch_bounds__(256) void k_scanA(const u32* __restrict__ deg, u32* __restrict__ part){
  __shared__ u32 red[256];
  int b = blockIdx.x, t = threadIdx.x;
  int c0 = b*ECHUNK, c1 = c0+ECHUNK; if (c1 > NENT) c1 = NENT; if (c0 > NENT) c0 = NENT;
  u32 s=0;
  for (int n=c0+t; n<c1; n+=256) s += deg[n];
  red[t]=s; __syncthreads();
  for (int m=128;m>=1;m>>=1){ if (t<m) red[t]+=red[t+m]; __syncthreads(); }
  if (t==0) part[b]=red[0];
}

// ---- stage R: per-rel scan of bhist columns (512 blocks, 2/thread) ----
__global__ __launch_bounds__(256) void k_scanR(const u32* __restrict__ bhist,
                                               u32* __restrict__ rbase, u32* __restrict__ rtot){
  __shared__ u32 sd[256];
  int r = blockIdx.x, t = threadIdx.x;
  u32 v0 = bhist[(size_t)(2*t)*256 + r];
  u32 v1 = bhist[(size_t)(2*t+1)*256 + r];
  u32 v = v0+v1;
  sd[t]=v; __syncthreads();
  for (int o=1;o<256;o<<=1){ u32 x=(t>=o)?sd[t-o]:0u; __syncthreads(); sd[t]+=x; __syncthreads(); }
  u32 ex = sd[t]-v;
  rbase[(size_t)r*NB + 2*t]   = ex;
  rbase[(size_t)r*NB + 2*t+1] = ex+v0;
  if (t==255) rtot[r] = sd[255];
}

// ---- stage B: scan part[256] -> base; scan rtot -> roff/relcntf ----
__global__ __launch_bounds__(256) void k_scanB(const u32* __restrict__ part, u32* __restrict__ base,
                                               u32* __restrict__ offs,
                                               const u32* __restrict__ rtot, u32* __restrict__ roff,
                                               float* __restrict__ relcntf){
  __shared__ u32 sd[256];
  int t = threadIdx.x;
  u32 v = part[t];
  sd[t]=v; __syncthreads();
  for (int o=1;o<256;o<<=1){ u32 x=(t>=o)?sd[t-o]:0u; __syncthreads(); sd[t]+=x; __syncthreads(); }
  base[t] = sd[t]-v;
  if (t==255) offs[NENT] = sd[255];
  __syncthreads();
  u32 rv = (t<NREL)? rtot[t] : 0u;
  sd[t]=rv; __syncthreads();
  for (int o=1;o<256;o<<=1){ u32 x=(t>=o)?sd[t-o]:0u; __syncthreads(); sd[t]+=x; __syncthreads(); }
  if (t<NREL){ roff[t]=sd[t]-rv; relcntf[t]=(float)rv; }
  if (t==NREL-1) roff[NREL]=sd[t];
}

// ---- stage C: per-chunk exclusive scan -> offs ----
__global__ __launch_bounds__(256) void k_scanC(const u32* __restrict__ deg, const u32* __restrict__ base,
                                               u32* __restrict__ offs){
  __shared__ u32 sd[256];
  int b = blockIdx.x, t = threadIdx.x;
  int c0 = b*ECHUNK;
  int cend = c0+ECHUNK; if (cend > NENT) cend = NENT;
  int n0 = c0 + 2*t;
  u32 d0 = (n0   < cend)? deg[n0]   : 0u;
  u32 d1 = (n0+1 < cend)? deg[n0+1] : 0u;
  u32 v = d0+d1;
  sd[t]=v; __syncthreads();
  for (int o=1;o<256;o<<=1){ u32 x=(t>=o)?sd[t-o]:0u; __syncthreads(); sd[t]+=x; __syncthreads(); }
  u32 ex = base[b] + sd[t]-v;
  if (n0   < cend) offs[n0]   = ex;
  if (n0+1 < cend) offs[n0+1] = ex+d0;
}

// ---- pass B: fill incidence lists (rel part atomic-free, packed endpoints) ----
__global__ __launch_bounds__(256) void k_incB(const int* __restrict__ trip,
                      const u32* __restrict__ offs, u32* __restrict__ cur,
                      const u32* __restrict__ roff, const u32* __restrict__ rbase,
                      u32* __restrict__ inc, u64* __restrict__ rele64){
  __shared__ u32 lh[256];
  int t = threadIdx.x, b = blockIdx.x;
  lh[t] = 0u;
  __syncthreads();
  int e0 = b*CHUNK, e1 = e0+CHUNK; if (e1 > E_EDGES) e1 = E_EDGES;
  for (int e=e0+t; e<e1; e+=256){
    int3 tr = ((const int3*)trip)[e];
    u32 p0 = offs[tr.x] + atomicAdd(&cur[tr.x], 1u);
    inc[p0] = (u32)tr.y | ((u32)tr.z<<17);
    u32 p1 = offs[tr.y] + atomicAdd(&cur[tr.y], 1u);
    inc[p1] = (u32)tr.x | ((u32)tr.z<<17) | (1u<<25);
    u32 loff = atomicAdd(&lh[tr.z], 1u);
    rele64[roff[tr.z] + rbase[(u32)tr.z*NB + b] + loff] = (u64)(u32)tr.x | ((u64)(u32)tr.y<<17);
  }
}

// ---- bn0 entity-column stats (degree-weighted) ----
__global__ void k_entstats(const float* __restrict__ ent, const u32* __restrict__ deg,
                           float* __restrict__ S1, float* __restrict__ S2){
  int d = threadIdx.x;            // 128, d<100 active
  if (d >= DIM) return;
  int n0 = blockIdx.x*256;
  int nend = n0+256; if (nend > NENT) nend = NENT;
  float s1=0.f, s2=0.f;
  for (int n=n0;n<nend;n++){
    float w = (float)deg[n];
    float x = ent[(size_t)n*DIM + d];
    s1 += w*x; s2 += w*x*x;
  }
  atomicAdd(&S1[d], s1);
  atomicAdd(&S2[d], s2);
}

__global__ void k_relstats(const float* __restrict__ rel, const float* __restrict__ relcnt, float* __restrict__ S2r){
  int d = threadIdx.x;
  if (d >= DIM) return;
  float s=0.f;
  for (int r=0;r<NREL;r++){
    float x = rel[r*DIM+d];
    s += relcnt[r]*x*x;
  }
  S2r[d] = s;
}

__global__ void k_scale0(const float* __restrict__ g0, const float* __restrict__ b0,
                         const float* __restrict__ S1, const float* __restrict__ S2, const float* __restrict__ S2r,
                         float* __restrict__ scale0, float* __restrict__ shift0){
  int j = threadIdx.x;            // 320
  if (j >= TDIM) return;
  float mean, var;
  if (j < 200){
    int d = (j<100)? j : j-100;
    mean = S1[d] * (1.0f/TWO_E);
    var  = S2[d] * (1.0f/TWO_E) - mean*mean;
  } else {
    mean = 0.0f;
    var  = S2r[j-200] * (1.0f/E_EDGES);
  }
  float sc = g0[j] * rsqrtf(var + BN_EPS);
  scale0[j] = sc;
  shift0[j] = b0[j] - mean*sc;
}

__global__ void k_foldW(const float* __restrict__ aW, const float* __restrict__ scale0,
                        float* __restrict__ Wpt, float* __restrict__ Wrelt){
  int idx = blockIdx.x*256 + threadIdx.x;
  if (idx < 20000){
    int d = idx/200, kk = idx%200;
    int k = (kk<100)? kk : kk-100;
    int j = (kk<100)? d : 100+d;
    Wpt[idx] = aW[k*TDIM + j] * scale0[j];
  } else if (idx < 30000){
    int i2 = idx - 20000;
    int d = i2/100, k = i2%100;
    Wrelt[i2] = aW[k*TDIM + 200 + d] * scale0[200+d];
  }
}

__global__ void k_bp(const float* __restrict__ aW, const float* __restrict__ ab,
                     const float* __restrict__ shift0, float* __restrict__ bp){
  int k = blockIdx.x;
  int l = threadIdx.x;            // 64
  float s=0.f;
  for (int j=l;j<TDIM;j+=64) s += aW[k*TDIM+j] * shift0[j];
  #pragma unroll
  for (int m=32;m>=1;m>>=1) s += __shfl_xor(s, m, 64);
  if (l==0) bp[k] = s + ab[k];
}

__global__ void k_V(const float* __restrict__ rel, const float* __restrict__ Wrelt, float* __restrict__ V){
  __shared__ float rf[DIM];
  int r = blockIdx.x;
  int k = threadIdx.x;            // 128
  if (k < DIM) rf[k] = rel[r*DIM+k];
  __syncthreads();
  if (k >= DIM) return;
  float s=0.f;
  for (int d=0;d<DIM;d++) s += Wrelt[d*DIM+k]*rf[d];
  V[r*DIM+k] = s;
}

// ---- UEp[n][256] bf16: U0 at col 0..99, U1 at col 128..227 ----
__global__ __launch_bounds__(256) void k_U(const float* __restrict__ ent, const float* __restrict__ Wpt,
                                           u16* __restrict__ UEp){
  __shared__ float sh[DIM][36];
  int n0 = blockIdx.x*32;         // 3125*32 = 100000
  for (int idx=threadIdx.x; idx<32*DIM; idx+=256){
    int n = idx/DIM, d = idx%DIM;
    sh[d][n] = ent[(size_t)(n0+n)*DIM + d];
  }
  __syncthreads();
  int kk = threadIdx.x;
  if (kk >= 200) return;
  float acc[32];
  #pragma unroll
  for (int i=0;i<32;i++) acc[i]=0.f;
  for (int d=0;d<DIM;d++){
    float w = Wpt[d*200+kk];
    #pragma unroll
    for (int i=0;i<32;i++) acc[i] += w*sh[d][i];
  }
  int col = (kk<100)? kk : (28+kk);   // 128 + (kk-100)
  for (int i=0;i<32;i++) UEp[(size_t)(n0+i)*PITCH + col] = f2bf(acc[i]);
}

// ---- bn1 stats over 2E rows of c_pre (edge sweep, 4 row gathers) ----
__global__ __launch_bounds__(256) void k_cstats(const int* __restrict__ trip,
    const u16* __restrict__ UEp, const float* __restrict__ V, const float* __restrict__ bp,
    float* __restrict__ Sc, float* __restrict__ Sc2){
  __shared__ float scB[DIM], sc2B[DIM];
  for (int i=threadIdx.x;i<DIM;i+=256){ scB[i]=0.f; sc2B[i]=0.f; }
  __syncthreads();
  int lane = threadIdx.x & 31;
  int slot = (blockIdx.x*256 + threadIdx.x) >> 5;
  int nslots = gridDim.x*8;
  bool act = lane < 25;
  int dbase = lane*4;
  float bpv[4]={0,0,0,0};
  if (act) ld4f(bp+dbase, bpv);
  float sc[4]={0,0,0,0}, sc2[4]={0,0,0,0};
  for (int e=slot; e<E_EDGES; e+=nslots){
    int3 t = ((const int3*)trip)[e];
    if (act){
      const u16* rx = UEp + (size_t)t.x*PITCH;
      const u16* ry = UEp + (size_t)t.y*PITCH;
      float P[4],Q[4],R[4],S[4],Vv[4];
      ld4a(rx+dbase, P);          // U0[t0]
      ld4a(ry+128+dbase, Q);      // U1[t1]
      ld4a(ry+dbase, R);          // U0[t1]
      ld4a(rx+128+dbase, S);      // U1[t0]
      ld4f(V+(size_t)t.z*DIM+dbase, Vv);
      #pragma unroll
      for (int i=0;i<4;i++){
        float cf = P[i]+Q[i]+Vv[i]+bpv[i];
        float ci = R[i]+S[i]-Vv[i]+bpv[i];
        sc[i]  += cf+ci;
        sc2[i] += cf*cf + ci*ci;
      }
    }
  }
  if (act){
    #pragma unroll
    for (int i=0;i<4;i++){ atomicAdd(&scB[dbase+i], sc[i]); atomicAdd(&sc2B[dbase+i], sc2[i]); }
  }
  __syncthreads();
  for (int i=threadIdx.x;i<DIM;i+=256){ atomicAdd(&Sc[i], scB[i]); atomicAdd(&Sc2[i], sc2B[i]); }
}

// ---- bn1 affine + attention vector w + scalar C ----
__global__ void k_bn1x(const float* __restrict__ g1, const float* __restrict__ b1,
                       const float* __restrict__ Sc, const float* __restrict__ Sc2,
                       const float* __restrict__ bp, const float* __restrict__ a2W, const float* __restrict__ a2b,
                       float* __restrict__ scale1, float* __restrict__ shift1,
                       float* __restrict__ wvec, float* __restrict__ consts){
  __shared__ float red[128];
  int k = threadIdx.x;            // 128
  float contrib = 0.f;
  if (k < DIM){
    float mean = Sc[k]*(1.0f/TWO_E);
    float var  = Sc2[k]*(1.0f/TWO_E) - mean*mean;
    float s = g1[k] * rsqrtf(var + BN_EPS);
    float sh = b1[k] - mean*s;
    float a2 = a2W[k];
    scale1[k] = s;
    shift1[k] = sh;
    float wv = s*a2;
    wvec[k] = wv;
    contrib = bp[k]*wv + sh*a2;
  }
  red[k] = contrib;
  __syncthreads();
  for (int m=64;m>=1;m>>=1){ if (k<m) red[k]+=red[k+m]; __syncthreads(); }
  if (k==0) consts[0] = red[0] + a2b[0];
}

// ---- phi0[n]=U0[n].w, phi1[n]=U1[n].w ----
__global__ __launch_bounds__(256) void k_phi(const u16* __restrict__ UEp, const float* __restrict__ wvec,
                                             float* __restrict__ phi0, float* __restrict__ phi1){
  int lane = threadIdx.x & 31;
  int n = blockIdx.x*8 + (threadIdx.x>>5);
  bool act = lane < 25;
  int dbase = lane*4;
  float w4[4]={0,0,0,0};
  float p0=0.f, p1=0.f;
  if (act){
    ld4f(wvec+dbase, w4);
    float P[4], Q[4];
    ld4a(UEp + (size_t)n*PITCH + dbase, P);
    ld4a(UEp + (size_t)n*PITCH + 128 + dbase, Q);
    #pragma unroll
    for (int i=0;i<4;i++){ p0 += P[i]*w4[i]; p1 += Q[i]*w4[i]; }
  }
  #pragma unroll
  for (int m=16;m>=1;m>>=1){ p0 += __shfl_xor(p0,m,32); p1 += __shfl_xor(p1,m,32); }
  if (lane==0){ phi0[n]=p0; phi1[n]=p1; }
}

// ---- psi[r]=V[r].w ----
__global__ void k_psi(const float* __restrict__ V, const float* __restrict__ wvec, float* __restrict__ psi){
  __shared__ float w[DIM];
  int t = threadIdx.x;            // 256
  if (t < DIM) w[t] = wvec[t];
  __syncthreads();
  if (t >= NREL) return;
  float s=0.f;
  for (int k=0;k<DIM;k++) s += V[t*DIM+k]*w[k];
  psi[t] = s;
}

// ---- entity aggregation: one 32-lane slot per entity, zero atomics ----
__global__ __launch_bounds__(256) void k_aggr_ent(const u32* __restrict__ offs, const u32* __restrict__ inc,
    const u16* __restrict__ UEp, const float* __restrict__ V,
    const float* __restrict__ phi0, const float* __restrict__ phi1, const float* __restrict__ psi,
    const float* __restrict__ consts, const float* __restrict__ bp,
    const float* __restrict__ scale1, const float* __restrict__ shift1,
    float* __restrict__ out){
  int lane = threadIdx.x & 31;
  int n = blockIdx.x*8 + (threadIdx.x>>5);
  bool act = lane < 25;
  int dbase = lane*4;
  u32 o0 = offs[n], o1 = offs[n+1];
  float C = consts[0];
  float p0n = phi0[n];
  float acc[4]={0,0,0,0};
  float wsum=0.f;
  for (u32 i=o0; i<o1; i++){
    u32 pk = inc[i];
    u32 other = pk & 0x1FFFFu;
    u32 rr = (pk>>17) & 0xFFu;
    bool neg = (pk>>25) != 0u;
    float ps = psi[rr];
    float t = p0n + phi1[other] + (neg ? -ps : ps) + C;
    float w = ewt(t);
    wsum += w;
    if (act){
      float B[4], Vv[4];
      ld4a(UEp + (size_t)other*PITCH + 128 + dbase, B);
      ld4f(V + (size_t)rr*DIM + dbase, Vv);
      float sg = neg ? -1.f : 1.f;
      #pragma unroll
      for (int i2=0;i2<4;i2++) acc[i2] += w*(B[i2]+sg*Vv[i2]);
    }
  }
  if (act){
    float o4[4];
    if (o1 == o0){
      o4[0]=o4[1]=o4[2]=o4[3]=0.f;
    } else {
      float P[4], bp4[4], s14[4], sh4[4];
      ld4a(UEp + (size_t)n*PITCH + dbase, P);
      ld4f(bp+dbase, bp4);
      ld4f(scale1+dbase, s14);
      ld4f(shift1+dbase, sh4);
      float inv = __frcp_rn(wsum);
      #pragma unroll
      for (int i2=0;i2<4;i2++){
        float v = (P[i2]+bp4[i2])*s14[i2] + sh4[i2] + s14[i2]*acc[i2]*inv;
        o4[i2] = eluf(v);
      }
    }
    *(float4*)(out + (size_t)n*DIM + dbase) = make_float4(o4[0],o4[1],o4[2],o4[3]);
  }
}

// ---- rel aggregation: NREL*RSEG blocks, LDS reduce + one atomic burst/block ----
__global__ __launch_bounds__(256) void k_aggr_relP(
    const u32* __restrict__ roff, const u64* __restrict__ rele64,
    const u16* __restrict__ UEp, const float* __restrict__ V,
    const float* __restrict__ phi0, const float* __restrict__ phi1, const float* __restrict__ psi,
    const float* __restrict__ consts, const float* __restrict__ bp,
    const float* __restrict__ scale1, const float* __restrict__ shift1,
    float* __restrict__ relacc){
  __shared__ float red[8][104];
  int r   = blockIdx.x / RSEG;
  int seg = blockIdx.x % RSEG;
  int lane = threadIdx.x & 31;
  int slot = threadIdx.x >> 5;    // 8 slots
  bool act = lane < 25;
  int dbase = lane*4;
  float C = consts[0];
  float psir = psi[r];
  float bp4[4]={0,0,0,0}, s14[4]={0,0,0,0}, sh4[4]={0,0,0,0}, Vv[4]={0,0,0,0};
  if (act){
    ld4f(bp+dbase, bp4);
    ld4f(scale1+dbase, s14);
    ld4f(shift1+dbase, sh4);
    ld4f(V + (size_t)r*DIM + dbase, Vv);
  }
  u32 q0 = roff[r], q1 = roff[r+1];
  float acc[4]={0,0,0,0};
  for (u32 q = q0 + (u32)(seg*8+slot); q < q1; q += RSEG*8){
    u64 pk = rele64[q];
    u32 t0 = (u32)(pk & 0x1FFFFu);
    u32 t1 = (u32)((pk>>17) & 0x1FFFFu);
    float tf = phi0[t0] + phi1[t1] + psir + C;
    float ti = phi0[t1] + phi1[t0] - psir + C;
    float ef = ewt(tf);
    float ei = ewt(ti);
    if (act){
      const u16* rx = UEp + (size_t)t0*PITCH;
      const u16* ry = UEp + (size_t)t1*PITCH;
      float P[4],Q[4],R[4],S[4];
      ld4a(rx+dbase, P);
      ld4a(ry+128+dbase, Q);
      ld4a(ry+dbase, R);
      ld4a(rx+128+dbase, S);
      #pragma unroll
      for (int i=0;i<4;i++){
        float cf = (P[i]+Q[i]+Vv[i]+bp4[i])*s14[i] + sh4[i];
        float ci = (R[i]+S[i]-Vv[i]+bp4[i])*s14[i] + sh4[i];
        acc[i] += ef*cf - ei*ci;
      }
    }
  }
  if (act){
    #pragma unroll
    for (int i=0;i<4;i++) red[slot][dbase+i] = acc[i];
  }
  __syncthreads();
  int k = threadIdx.x;
  if (k < DIM){
    float s = 0.f;
    #pragma unroll
    for (int sl=0;sl<8;sl++) s += red[sl][k];
    atomicAdd(&relacc[(size_t)r*DIM + k], s);
  }
}

// ---- finalize h_rel ----
__global__ void k_out_rel(const float* __restrict__ relacc, const float* __restrict__ relcnt,
                          float* __restrict__ out){
  int idx = blockIdx.x*256 + threadIdx.x;
  if (idx >= NREL*DIM) return;
  int r = idx/DIM;
  float cn = relcnt[r]; if (cn < 1.f) cn = 1.f;
  out[(size_t)NENT*DIM + idx] = eluf(relacc[idx]/cn);
}

extern "C" void kernel_launch(void* const* d_in, const int* in_sizes, int n_in,
                              void* d_out, int out_size, void* d_ws, size_t ws_size,
                              hipStream_t stream){
  const int*   trip = (const int*)d_in[0];
  const float* ent  = (const float*)d_in[1];
  const float* rel  = (const float*)d_in[2];
  const float* aW   = (const float*)d_in[3];
  const float* ab   = (const float*)d_in[4];
  const float* a2W  = (const float*)d_in[5];
  const float* a2b  = (const float*)d_in[6];
  const float* g0   = (const float*)d_in[7];
  const float* b0   = (const float*)d_in[8];
  const float* g1   = (const float*)d_in[9];
  const float* b1   = (const float*)d_in[10];
  float* out = (float*)d_out;
  float* wsf = (float*)d_ws;
  if (ws_size < TOTAL_F*sizeof(float)) return;
  u16* UEp  = (u16*)(wsf + OFF_UE);
  u32* deg  = (u32*)(wsf + OFF_DEG);
  u32* cur  = (u32*)(wsf + OFF_CUR);
  u32* offs = (u32*)(wsf + OFF_OFFS);
  u32* roff = (u32*)(wsf + OFF_ROFF);
  u32* bhist= (u32*)(wsf + OFF_BHIST);
  u32* rbase= (u32*)(wsf + OFF_RBASE);
  u32* part = (u32*)(wsf + OFF_PART);
  u32* base = (u32*)(wsf + OFF_BASE);
  u32* rtot = (u32*)(wsf + OFF_RTOT);
  u32* inc  = (u32*)(wsf + OFF_INC);
  u64* rele = (u64*)(wsf + OFF_RELE64);

  hipMemsetAsync(d_ws, 0, ZERO_END*sizeof(float), stream);

  k_histA<<<dim3(NB), dim3(256), 0, stream>>>(trip, deg, bhist);
  k_entstats<<<dim3((NENT+255)/256), dim3(128), 0, stream>>>(ent, deg, wsf+OFF_S1, wsf+OFF_S2);
  k_scanA<<<dim3(256), dim3(256), 0, stream>>>(deg, part);
  k_scanR<<<dim3(NREL), dim3(256), 0, stream>>>(bhist, rbase, rtot);
  k_scanB<<<dim3(1), dim3(256), 0, stream>>>(part, base, offs, rtot, roff, wsf+OFF_RELCNTF);
  k_scanC<<<dim3(256), dim3(256), 0, stream>>>(deg, base, offs);
  k_relstats<<<dim3(1), dim3(128), 0, stream>>>(rel, wsf+OFF_RELCNTF, wsf+OFF_S2R);
  k_scale0<<<dim3(1), dim3(320), 0, stream>>>(g0, b0, wsf+OFF_S1, wsf+OFF_S2, wsf+OFF_S2R,
                                              wsf+OFF_SCALE0, wsf+OFF_SHIFT0);
  k_foldW<<<dim3(118), dim3(256), 0, stream>>>(aW, wsf+OFF_SCALE0, wsf+OFF_WPT, wsf+OFF_WRELT);
  k_bp<<<dim3(100), dim3(64), 0, stream>>>(aW, ab, wsf+OFF_SHIFT0, wsf+OFF_BP);
  k_V<<<dim3(NREL), dim3(128), 0, stream>>>(rel, wsf+OFF_WRELT, wsf+OFF_V);
  k_U<<<dim3(NENT/32), dim3(256), 0, stream>>>(ent, wsf+OFF_WPT, UEp);
  k_incB<<<dim3(NB), dim3(256), 0, stream>>>(trip, offs, cur, roff, rbase, inc, rele);
  k_cstats<<<dim3(2048), dim3(256), 0, stream>>>(trip, UEp, wsf+OFF_V, wsf+OFF_BP,
                                                 wsf+OFF_SC, wsf+OFF_SC2);
  k_bn1x<<<dim3(1), dim3(128), 0, stream>>>(g1, b1, wsf+OFF_SC, wsf+OFF_SC2, wsf+OFF_BP, a2W, a2b,
                                            wsf+OFF_SCALE1, wsf+OFF_SHIFT1, wsf+OFF_WVEC, wsf+OFF_CONST);
  k_phi<<<dim3(NENT/8), dim3(256), 0, stream>>>(UEp, wsf+OFF_WVEC, wsf+OFF_PHI0, wsf+OFF_PHI1);
  k_psi<<<dim3(1), dim3(256), 0, stream>>>(wsf+OFF_V, wsf+OFF_WVEC, wsf+OFF_PSI);
  k_aggr_ent<<<dim3(NENT/8), dim3(256), 0, stream>>>(offs, inc, UEp, wsf+OFF_V,
                                                     wsf+OFF_PHI0, wsf+OFF_PHI1, wsf+OFF_PSI,
                                                     wsf+OFF_CONST, wsf+OFF_BP,
                                                     wsf+OFF_SCALE1, wsf+OFF_SHIFT1, out);
  k_aggr_relP<<<dim3(NREL*RSEG), dim3(256), 0, stream>>>(roff, rele, UEp, wsf+OFF_V,
                                                   wsf+OFF_PHI0, wsf+OFF_PHI1, wsf+OFF_PSI,
                                                   wsf+OFF_CONST, wsf+OFF_BP,
                                                   wsf+OFF_SCALE1, wsf+OFF_SHIFT1,
                                                   wsf+OFF_RELACC);
  k_out_rel<<<dim3((NREL*DIM+255)/256), dim3(256), 0, stream>>>(wsf+OFF_RELACC, wsf+OFF_RELCNTF, out);
}